// Round 8
// baseline (3164.603 us; speedup 1.0000x reference)
//
#include <hip/hip_runtime.h>
#include <hip/hip_bf16.h>

typedef _Float16 half8_t __attribute__((ext_vector_type(8)));
typedef _Float16 half4_t __attribute__((ext_vector_type(4)));
typedef _Float16 half2_t __attribute__((ext_vector_type(2)));
typedef float float4_t __attribute__((ext_vector_type(4)));
typedef unsigned int uint2_t __attribute__((ext_vector_type(2)));

#define TT 1024
#define BB 128
#define EE 128
#define HH 128
#define NTAG 64
#define ASTR 144  // [batch][hu] LDS panel stride (f16) — R6-proven for the b128 read pattern

__device__ __forceinline__ float fast_exp(float x) {
  return __builtin_amdgcn_exp2f(x * 1.44269504088896f);
}
// LDS-only barrier: does NOT drain vmcnt -> global loads/stores stay in flight.
__device__ __forceinline__ void lds_barrier() {
  asm volatile("s_waitcnt lgkmcnt(0)\n\ts_barrier" ::: "memory");
}
// Single-wave LDS write->read fence.
__device__ __forceinline__ void lds_fence() {
  asm volatile("s_waitcnt lgkmcnt(0)" ::: "memory");
}
__device__ __forceinline__ half2_t cvt_pk(float a, float b) {
  return __builtin_bit_cast(half2_t, __builtin_amdgcn_cvt_pkrtz(a, b));
}
__device__ __forceinline__ half2_t h2bc(float v) {
  _Float16 h = (_Float16)v;
  half2_t r; r[0] = h; r[1] = h;
  return r;
}
__device__ __forceinline__ half8_t h8bc(float v) {
  _Float16 h = (_Float16)v;
  half8_t r;
#pragma unroll
  for (int i = 0; i < 8; ++i) r[i] = h;
  return r;
}
// max over the 4 quads (lane bits 4,5) for each n16 column — pure VALU (permlane swaps)
__device__ __forceinline__ float quad_max4(float v) {
  unsigned a = __builtin_bit_cast(unsigned, v);
  uint2_t r = __builtin_amdgcn_permlane32_swap(a, a, false, false);
  float m = fmaxf(__builtin_bit_cast(float, r[0]), __builtin_bit_cast(float, r[1]));
  unsigned b = __builtin_bit_cast(unsigned, m);
  uint2_t s = __builtin_amdgcn_permlane16_swap(b, b, false, false);
  return fmaxf(__builtin_bit_cast(float, s[0]), __builtin_bit_cast(float, s[1]));
}
// deg-5 odd tanh poly (fit at 1, 1.6; clamp +-1.6): 6 pk instrs
__device__ __forceinline__ half2_t tanh6(half2_t x) {
  half2_t y = __builtin_elementwise_min(__builtin_elementwise_max(x, h2bc(-1.6f)), h2bc(1.6f));
  half2_t u = y * y;
  half2_t p = u * h2bc(0.04667f) + h2bc(-0.28507f);
  p = u * p + h2bc(1.0f);
  return y * p;
}
// sigmoid, x/2 folded into coefficients: 6 pk instrs
__device__ __forceinline__ half2_t sig6(half2_t x) {
  half2_t y = __builtin_elementwise_min(__builtin_elementwise_max(x, h2bc(-3.2f)), h2bc(3.2f));
  half2_t u = y * y;
  half2_t q = u * h2bc(0.00072921875f) + h2bc(-0.017816875f);
  q = u * q + h2bc(0.25f);
  return y * q + h2bc(0.5f);
}

// ---------------------------------------------------------------- init + embed (fused, independent)
__global__ __launch_bounds__(256) void initembed_kernel(const int* __restrict__ kmers,
                                                        const float* __restrict__ emb,
                                                        half4_t* __restrict__ x,
                                                        float4_t* __restrict__ state) {
  if (blockIdx.x < 48) {
    state[blockIdx.x * 256 + threadIdx.x] = (float4_t){0.f, 0.f, 0.f, 0.f};
    return;
  }
  const int g = (blockIdx.x - 48) * 256 + threadIdx.x;
  const int row = g >> 5, seg = g & 31;
  const int km = kmers[row];
  const float4_t v = ((const float4_t*)(emb + (size_t)km * EE))[seg];
  half4_t o;
  o[0] = (_Float16)v[0]; o[1] = (_Float16)v[1];
  o[2] = (_Float16)v[2]; o[3] = (_Float16)v[3];
  x[(size_t)row * 32 + seg] = o;
}

// ---------------------------------------------------------------- xg body (device)
// Orientation: A = W_ih (regs), B = x^T (b128 global loads), C rows=hu-part, col=batch.
__device__ __forceinline__ void xg_body(
    int wg, int tid, const _Float16* __restrict__ x,
    const float* __restrict__ w_ih_f, const float* __restrict__ b_ih_f, const float* __restrict__ b_hh_f,
    const float* __restrict__ w_ih_b, const float* __restrict__ b_ih_b, const float* __restrict__ b_hh_b,
    _Float16* __restrict__ xgbuf, int s, int Tseg) {
  const int nt = Tseg >> 4;
  const int dir = wg / (8 * nt);
  const int rem = wg - dir * 8 * nt;
  const int chunk = rem / nt;
  const int tb = rem - chunk * nt;
  const int wave = tid >> 6, lane = tid & 63;
  const int n16 = lane & 15, quad = lane >> 4;

  const float* wih = dir ? w_ih_b : w_ih_f;
  const float* bih = dir ? b_ih_b : b_ih_f;
  const float* bhh = dir ? b_hh_b : b_hh_f;

  half8_t wf[4][4];
#pragma unroll
  for (int g = 0; g < 4; ++g) {
    const int row = g * HH + wave * 16 + n16;
#pragma unroll
    for (int kf = 0; kf < 4; ++kf) {
      const float* src = wih + row * EE + kf * 32 + quad * 8;
#pragma unroll
      for (int i = 0; i < 8; ++i) wf[g][kf][i] = (_Float16)src[i];
    }
  }
  float4_t bias4[4];
#pragma unroll
  for (int g = 0; g < 4; ++g) {
    const int row = g * HH + wave * 16 + quad * 4;
    const float4_t bi = *(const float4_t*)(bih + row);
    const float4_t bh = *(const float4_t*)(bhh + row);
    bias4[g] = bi + bh;
  }

  const int l0 = tb * 16;
  half8_t xb[4];
  {
    const int te = dir ? (TT - 1 - (s * Tseg + l0)) : (s * Tseg + l0);
#pragma unroll
    for (int kf = 0; kf < 4; ++kf)
      xb[kf] = *(const half8_t*)(x + ((size_t)te * BB + chunk * 16 + n16) * EE + kf * 32 + quad * 8);
  }
  for (int u = 0; u < 16; ++u) {
    const int l = l0 + u;
    half8_t xn[4] = {};
    if (u < 15) {
      const int tn = dir ? (TT - 1 - (s * Tseg + l + 1)) : (s * Tseg + l + 1);
#pragma unroll
      for (int kf = 0; kf < 4; ++kf)
        xn[kf] = *(const half8_t*)(x + ((size_t)tn * BB + chunk * 16 + n16) * EE + kf * 32 + quad * 8);
    }
    float4_t acc[4];
#pragma unroll
    for (int g = 0; g < 4; ++g) acc[g] = bias4[g];
#pragma unroll
    for (int kf = 0; kf < 4; ++kf)
#pragma unroll
      for (int g = 0; g < 4; ++g)
        acc[g] = __builtin_amdgcn_mfma_f32_16x16x32_f16(wf[g][kf], xb[kf], acc[g], 0, 0, 0);
    half8_t ho0, ho1;
#pragma unroll
    for (int r = 0; r < 4; ++r) {
      ho0[r] = (_Float16)acc[0][r];
      ho0[4 + r] = (_Float16)acc[1][r];
      ho1[r] = (_Float16)acc[2][r];
      ho1[4 + r] = (_Float16)acc[3][r];
    }
    _Float16* ob = xgbuf + (size_t)dir * Tseg * 65536 + (size_t)l * 65536 + chunk * 8192 +
                   wave * 1024 + lane * 16;
    *(half8_t*)ob = ho0;
    *(half8_t*)(ob + 8) = ho1;
#pragma unroll
    for (int kf = 0; kf < 4; ++kf) xb[kf] = xn[kf];
  }
}

// ---------------------------------------------------------------- standalone xg (first segment)
__global__ __launch_bounds__(512) void xg_kernel(
    const _Float16* __restrict__ x,
    const float* __restrict__ w_ih_f, const float* __restrict__ b_ih_f, const float* __restrict__ b_hh_f,
    const float* __restrict__ w_ih_b, const float* __restrict__ b_ih_b, const float* __restrict__ b_hh_b,
    _Float16* __restrict__ xgbuf, int s, int Tseg) {
  xg_body(blockIdx.x, threadIdx.x, x, w_ih_f, b_ih_f, b_hh_f, w_ih_b, b_ih_b, b_hh_b, xgbuf, s,
          Tseg);
}

// ---------------------------------------------------------------- fused: lstm(s) both dirs + xg(s+1)
// Blocks 0..7: ONE chunk each, BOTH direction chains in one 16-wave block (dir = wave>>3).
// Wave->SIMD round-robin puts 2 fwd + 2 bwd waves per SIMD: two INDEPENDENT dependency
// chains per SIMD, so one chain's LDS/MFMA/epilogue stalls are filled by the other.
// __launch_bounds__(1024, 4): min 4 waves/EU -> VGPR cap 128 (R7's default chose 8 -> 64 ->
// massive spills, FETCH/WRITE +110MB scratch). At VGPR<=128, 16 waves fill the CU's VGPR
// pool, so only 1 block/CU fits naturally -> xg blocks never land on the 8 LSTM CUs.
// Blocks >= 8: TWO xg units per 1024-thread block.
__global__ __launch_bounds__(1024, 4) void lstm_xg_kernel(
    const _Float16* __restrict__ xgrd, _Float16* __restrict__ xgwr,
    const _Float16* __restrict__ x,
    const float* __restrict__ w_hh_f, const float* __restrict__ w_hh_b,
    const float* __restrict__ w_ih_f, const float* __restrict__ b_ih_f, const float* __restrict__ b_hh_f,
    const float* __restrict__ w_ih_b, const float* __restrict__ b_ih_b, const float* __restrict__ b_hh_b,
    _Float16* __restrict__ h_cat, _Float16* __restrict__ h_state, float* __restrict__ c_state,
    int s, int sx, int Tseg) {
  __shared__ _Float16 A[2][2][16 * ASTR];  // [dir][buf][panel]

  if (blockIdx.x >= 8) {
    const int unit = (blockIdx.x - 8) * 2 + (threadIdx.x >> 9);
    xg_body(unit, threadIdx.x & 511, x, w_ih_f, b_ih_f, b_hh_f, w_ih_b, b_ih_b, b_hh_b, xgwr,
            sx, Tseg);
    return;
  }
  const int chunk = blockIdx.x;
  const int b0 = chunk * 16;
  const int tid = threadIdx.x;
  const int wave16 = tid >> 6, lane = tid & 63;
  const int dir = wave16 >> 3, w = wave16 & 7;
  const int n16 = lane & 15, quad = lane >> 4;
  const float* w_hh = dir ? w_hh_b : w_hh_f;

  half8_t wf[4][4];
#pragma unroll
  for (int g = 0; g < 4; ++g) {
    const int row = g * HH + w * 16 + n16;
#pragma unroll
    for (int kf = 0; kf < 4; ++kf) {
      const float* src = w_hh + row * HH + kf * 32 + quad * 8;
#pragma unroll
      for (int i = 0; i < 8; ++i) wf[g][kf][i] = (_Float16)src[i];
    }
  }
  // persistent state: layout identical to R5 ((dir*8+chunk)*8+w)
  const int sidx = (((dir * 8 + chunk) * 8 + w) * 64 + lane) * 4;
  half4_t h4 = *(const half4_t*)(h_state + sidx);
  float4_t c4 = *(const float4_t*)(c_state + sidx);
  half2_t c2[2];
  c2[0] = cvt_pk(c4[0], c4[1]);
  c2[1] = cvt_pk(c4[2], c4[3]);
  *(half4_t*)(&A[dir][0][n16 * ASTR + w * 16 + quad * 4]) = h4;  // seed h_{-1}

  const _Float16* xgw =
      xgrd + (size_t)dir * Tseg * 65536 + chunk * 8192 + w * 1024 + (size_t)lane * 16;
  half4_t hlast = h4;
  const float4_t z4 = {0.f, 0.f, 0.f, 0.f};
  const int te0 = dir ? (TT - 1 - s * Tseg) : (s * Tseg);
  _Float16* gp_run = h_cat + ((size_t)te0 * BB + b0 + n16) * 256 + dir * HH + w * 16 + quad * 4;
  const ptrdiff_t dstep = dir ? -(ptrdiff_t)32768 : (ptrdiff_t)32768;

  half8_t pf0[4], pf1[4];
#pragma unroll
  for (int j = 0; j < 4; ++j) {
    const _Float16* p = xgw + (size_t)j * 65536;
    pf0[j] = *(const half8_t*)p;
    pf1[j] = *(const half8_t*)(p + 8);
  }
  _Float16* const Ad0 = &A[dir][0][0];
  _Float16* const Ad1 = &A[dir][1][0];

#define LSTM_STEP(AB, AN, X0, X1)                                                          \
  {                                                                                        \
    const _Float16* Abp = AB;                                                              \
    _Float16* Anp = AN;                                                                    \
    half8_t hb0 = *(const half8_t*)(Abp + n16 * ASTR + 0 * 32 + quad * 8);                 \
    half8_t hb1 = *(const half8_t*)(Abp + n16 * ASTR + 1 * 32 + quad * 8);                 \
    half8_t hb2 = *(const half8_t*)(Abp + n16 * ASTR + 2 * 32 + quad * 8);                 \
    half8_t hb3 = *(const half8_t*)(Abp + n16 * ASTR + 3 * 32 + quad * 8);                 \
    float4_t acc[4];                                                                       \
    _Pragma("unroll") for (int g = 0; g < 4; ++g) {                                        \
      acc[g] = __builtin_amdgcn_mfma_f32_16x16x32_f16(wf[g][0], hb0, z4, 0, 0, 0);         \
    }                                                                                      \
    _Pragma("unroll") for (int g = 0; g < 4; ++g) {                                        \
      acc[g] = __builtin_amdgcn_mfma_f32_16x16x32_f16(wf[g][1], hb1, acc[g], 0, 0, 0);     \
    }                                                                                      \
    _Pragma("unroll") for (int g = 0; g < 4; ++g) {                                        \
      acc[g] = __builtin_amdgcn_mfma_f32_16x16x32_f16(wf[g][2], hb2, acc[g], 0, 0, 0);     \
    }                                                                                      \
    _Pragma("unroll") for (int g = 0; g < 4; ++g) {                                        \
      acc[g] = __builtin_amdgcn_mfma_f32_16x16x32_f16(wf[g][3], hb3, acc[g], 0, 0, 0);     \
    }                                                                                      \
    const half2_t* x0p = (const half2_t*)&X0;                                              \
    const half2_t* x1p = (const half2_t*)&X1;                                              \
    half4_t hstore;                                                                        \
    _Pragma("unroll") for (int p = 0; p < 2; ++p) {                                        \
      const half2_t i_ = sig6(cvt_pk(acc[0][2 * p], acc[0][2 * p + 1]) + x0p[p]);          \
      const half2_t f_ = sig6(cvt_pk(acc[1][2 * p], acc[1][2 * p + 1]) + x0p[2 + p]);      \
      const half2_t g_ = tanh6(cvt_pk(acc[2][2 * p], acc[2][2 * p + 1]) + x1p[p]);         \
      const half2_t o_ = sig6(cvt_pk(acc[3][2 * p], acc[3][2 * p + 1]) + x1p[2 + p]);      \
      c2[p] = f_ * c2[p] + i_ * g_;                                                        \
      const half2_t hh = o_ * tanh6(c2[p]);                                                \
      hstore[2 * p] = hh[0];                                                               \
      hstore[2 * p + 1] = hh[1];                                                           \
    }                                                                                      \
    *(half4_t*)(Anp + n16 * ASTR + w * 16 + quad * 4) = hstore;                            \
    *(half4_t*)gp_run = hstore;                                                            \
    hlast = hstore;                                                                        \
  }

  for (int il = 0; il < Tseg - 4; il += 4) {
#pragma unroll
    for (int j = 0; j < 4; ++j) {
      lds_barrier();
      if (j & 1) {
        LSTM_STEP(Ad1, Ad0, pf0[j], pf1[j]);
      } else {
        LSTM_STEP(Ad0, Ad1, pf0[j], pf1[j]);
      }
      const _Float16* p = xgw + (size_t)(il + j + 4) * 65536;
      pf0[j] = *(const half8_t*)p;
      pf1[j] = *(const half8_t*)(p + 8);
      gp_run += dstep;
    }
  }
#pragma unroll
  for (int j = 0; j < 4; ++j) {
    lds_barrier();
    if (j & 1) {
      LSTM_STEP(Ad1, Ad0, pf0[j], pf1[j]);
    } else {
      LSTM_STEP(Ad0, Ad1, pf0[j], pf1[j]);
    }
    gp_run += dstep;
  }
#undef LSTM_STEP

  *(half4_t*)(h_state + sidx) = hlast;
  c4[0] = (float)c2[0][0]; c4[1] = (float)c2[0][1];
  c4[2] = (float)c2[1][0]; c4[3] = (float)c2[1][1];
  *(float4_t*)(c_state + sidx) = c4;
}

// ---------------------------------------------------------------- emissions: em f32 + expem f16
__global__ __launch_bounds__(256) void emis_kernel(const _Float16* __restrict__ h_cat,
                                                   const float* __restrict__ w_proj,
                                                   const float* __restrict__ b_proj,
                                                   float* __restrict__ em,
                                                   _Float16* __restrict__ expem) {
  const int tid = threadIdx.x;
  const int wave = tid >> 6, lane = tid & 63;
  const int n16 = lane & 15, quad = lane >> 4;
  const size_t row0 = (size_t)blockIdx.x * 64 + wave * 16;

  half8_t bf[4][8];
#pragma unroll
  for (int nt = 0; nt < 4; ++nt) {
    const float* wp = w_proj + (nt * 16 + n16) * 256;
#pragma unroll
    for (int kf = 0; kf < 8; ++kf) {
      const int kb = kf * 32 + quad * 8;
#pragma unroll
      for (int i = 0; i < 8; ++i) bf[nt][kf][i] = (_Float16)wp[kb + i];
    }
  }
  float4_t acc[4];
#pragma unroll
  for (int nt = 0; nt < 4; ++nt) {
    const float bv = b_proj[nt * 16 + n16];
    acc[nt] = (float4_t){bv, bv, bv, bv};
  }
#pragma unroll
  for (int kf = 0; kf < 8; ++kf) {
    half8_t af = *(const half8_t*)(h_cat + (row0 + n16) * 256 + kf * 32 + quad * 8);
#pragma unroll
    for (int nt = 0; nt < 4; ++nt)
      acc[nt] = __builtin_amdgcn_mfma_f32_16x16x32_f16(af, bf[nt][kf], acc[nt], 0, 0, 0);
  }
#pragma unroll
  for (int nt = 0; nt < 4; ++nt)
#pragma unroll
    for (int r = 0; r < 4; ++r) {
      const size_t idx = (row0 + quad * 4 + r) * NTAG + nt * 16 + n16;
      em[idx] = acc[nt][r];
      expem[idx] = (_Float16)fast_exp(acc[nt][r]);
    }
}

// ---------------------------------------------------------------- segment-parallel CRF matrices
// 2048 chains (128 batches x 16 segments), 1 wave each: N <- diag(g_t) (E^T N), N init = I.
// Stored as Nbuf[b][s][c][k] = N[k][c] = P_s[c][k]. Blocks >= 2048: CRF numerator.
__global__ __launch_bounds__(64) void mcrf_kernel(const float* __restrict__ em,
                                                  const _Float16* __restrict__ expem,
                                                  const float* __restrict__ trans,
                                                  const int* __restrict__ tags,
                                                  const float* __restrict__ start_trans,
                                                  const float* __restrict__ end_trans,
                                                  _Float16* __restrict__ Nbuf,
                                                  float* __restrict__ lzbuf,
                                                  float* __restrict__ num) {
  const int lane = threadIdx.x;
  if (blockIdx.x >= 2048) {  // ---------------- numerator (1 wave per batch)
    const int nb = blockIdx.x - 2048;
    const int tg = tags[nb];
    float acc = 0.f;
    for (int t = lane; t < TT; t += 64)
      acc += em[((size_t)t * BB + nb) * NTAG + tg];
#pragma unroll
    for (int off = 32; off > 0; off >>= 1) acc += __shfl_xor(acc, off, 64);
    if (lane == 0)
      num[nb] = start_trans[tg] + end_trans[tg] + 1023.0f * trans[tg * NTAG + tg] + acc;
    return;
  }
  const int n16 = lane & 15, quad = lane >> 4;
  const int b = blockIdx.x >> 4;
  const int s = blockIdx.x & 15;

  half8_t efA[4][2];
#pragma unroll
  for (int mt = 0; mt < 4; ++mt)
#pragma unroll
    for (int kf = 0; kf < 2; ++kf)
#pragma unroll
      for (int i = 0; i < 8; ++i) {
        const int m = mt * 16 + n16, k = kf * 32 + quad * 8 + i;
        efA[mt][kf][i] = (_Float16)(fast_exp(trans[k * NTAG + m]) * 0.015625f);
      }

  half8_t pb[4][2];
#pragma unroll
  for (int tile = 0; tile < 4; ++tile)
#pragma unroll
    for (int kf = 0; kf < 2; ++kf)
#pragma unroll
      for (int i = 0; i < 8; ++i) {
        const int k = kf * 32 + quad * 8 + i;
        pb[tile][kf][i] = (_Float16)((k == tile * 16 + n16) ? 1.f : 0.f);
      }

  float lz2 = 0.f;
  const float4_t z4 = {0.f, 0.f, 0.f, 0.f};
  const _Float16* exb = expem + (size_t)b * NTAG;
  const int t0 = s * 64 + 1;
  const int nsteps = (s == 15) ? 63 : 64;

#define MCRF_CORE(PB0, PB1, NB0, NB1)                                                      \
  {                                                                                        \
    float4_t a0 = __builtin_amdgcn_mfma_f32_16x16x32_f16(efA[0][0], PB0, z4, 0, 0, 0);     \
    float4_t a1 = __builtin_amdgcn_mfma_f32_16x16x32_f16(efA[1][0], PB0, z4, 0, 0, 0);     \
    float4_t a2 = __builtin_amdgcn_mfma_f32_16x16x32_f16(efA[2][0], PB0, z4, 0, 0, 0);     \
    float4_t a3 = __builtin_amdgcn_mfma_f32_16x16x32_f16(efA[3][0], PB0, z4, 0, 0, 0);     \
    a0 = __builtin_amdgcn_mfma_f32_16x16x32_f16(efA[0][1], PB1, a0, 0, 0, 0);              \
    a1 = __builtin_amdgcn_mfma_f32_16x16x32_f16(efA[1][1], PB1, a1, 0, 0, 0);              \
    a2 = __builtin_amdgcn_mfma_f32_16x16x32_f16(efA[2][1], PB1, a2, 0, 0, 0);              \
    a3 = __builtin_amdgcn_mfma_f32_16x16x32_f16(efA[3][1], PB1, a3, 0, 0, 0);              \
    half2_t dpk[4][2];                                                                     \
    dpk[0][0] = cvt_pk(a0[0], a0[1]); dpk[0][1] = cvt_pk(a0[2], a0[3]);                    \
    dpk[1][0] = cvt_pk(a1[0], a1[1]); dpk[1][1] = cvt_pk(a1[2], a1[3]);                    \
    dpk[2][0] = cvt_pk(a2[0], a2[1]); dpk[2][1] = cvt_pk(a2[2], a2[3]);                    \
    dpk[3][0] = cvt_pk(a3[0], a3[1]); dpk[3][1] = cvt_pk(a3[2], a3[3]);                    \
    half2_t* wwp0 = (half2_t*)&NB0;                                                        \
    half2_t* wwp1 = (half2_t*)&NB1;                                                        \
    _Pragma("unroll") for (int kf = 0; kf < 2; ++kf) {                                     \
      half2_t* wp = kf ? wwp1 : wwp0;                                                      \
      _Pragma("unroll") for (int p = 0; p < 2; ++p) {                                      \
        const unsigned Xu = __builtin_bit_cast(unsigned, dpk[2 * kf][p]);                  \
        const unsigned Yu = __builtin_bit_cast(unsigned, dpk[2 * kf + 1][p]);              \
        uint2_t r1 = __builtin_amdgcn_permlane32_swap(Xu, Yu, false, false);               \
        uint2_t r2 = __builtin_amdgcn_permlane16_swap(r1[0], r1[1], false, false);         \
        wp[p] = __builtin_bit_cast(half2_t, r2[0]);                                        \
        wp[2 + p] = __builtin_bit_cast(half2_t, r2[1]);                                    \
      }                                                                                    \
    }                                                                                      \
  }

#define MSTEP(GC0, GC1, IT)                                                                \
  {                                                                                        \
    _Pragma("unroll") for (int tile = 0; tile < 4; ++tile) {                               \
      half8_t nb0, nb1;                                                                    \
      MCRF_CORE(pb[tile][0], pb[tile][1], nb0, nb1)                                        \
      pb[tile][0] = nb0 * GC0;                                                             \
      pb[tile][1] = nb1 * GC1;                                                             \
    }                                                                                      \
    if (((IT) & 15) == 15) {                                                               \
      half8_t m8 = __builtin_elementwise_max(pb[0][0], pb[0][1]);                          \
      m8 = __builtin_elementwise_max(m8, __builtin_elementwise_max(pb[1][0], pb[1][1]));   \
      m8 = __builtin_elementwise_max(m8, __builtin_elementwise_max(pb[2][0], pb[2][1]));   \
      m8 = __builtin_elementwise_max(m8, __builtin_elementwise_max(pb[3][0], pb[3][1]));   \
      float mm = (float)m8[0];                                                             \
      _Pragma("unroll") for (int i = 1; i < 8; ++i) mm = fmaxf(mm, (float)m8[i]);          \
      mm = quad_max4(mm);                                                                  \
      mm = fmaxf(mm, __shfl_xor(mm, 1, 64));                                               \
      mm = fmaxf(mm, __shfl_xor(mm, 2, 64));                                               \
      mm = fmaxf(mm, __shfl_xor(mm, 4, 64));                                               \
      mm = fmaxf(mm, __shfl_xor(mm, 8, 64));                                               \
      lz2 += __builtin_amdgcn_logf(mm);                                                    \
      const half8_t rc8 = h8bc(__builtin_amdgcn_rcpf(mm));                                 \
      _Pragma("unroll") for (int tile = 0; tile < 4; ++tile) {                             \
        pb[tile][0] *= rc8;                                                                \
        pb[tile][1] *= rc8;                                                                \
      }                                                                                    \
    }                                                                                      \
  }

  half8_t pre0[4], pre1[4];
#pragma unroll
  for (int j = 0; j < 4; ++j) {
    const size_t tt = (size_t)(t0 + j) * 8192;
    pre0[j] = *(const half8_t*)(exb + tt + quad * 8);
    pre1[j] = *(const half8_t*)(exb + tt + 32 + quad * 8);
  }
  int it = 0;
  const int full4 = nsteps >> 2;
  for (int grp = 0; grp < full4; ++grp) {
#pragma unroll
    for (int j = 0; j < 4; ++j) {
      const half8_t gc0 = pre0[j], gc1 = pre1[j];
      int tf = t0 + it + 4;
      tf = tf > 1023 ? 1023 : tf;
      const size_t tt = (size_t)tf * 8192;
      pre0[j] = *(const half8_t*)(exb + tt + quad * 8);
      pre1[j] = *(const half8_t*)(exb + tt + 32 + quad * 8);
      MSTEP(gc0, gc1, it)
      ++it;
    }
  }
  for (; it < nsteps; ++it) {
    const size_t tt = (size_t)(t0 + it) * 8192;
    const half8_t gc0 = *(const half8_t*)(exb + tt + quad * 8);
    const half8_t gc1 = *(const half8_t*)(exb + tt + 32 + quad * 8);
    MSTEP(gc0, gc1, it)
  }
#undef MSTEP
#undef MCRF_CORE

  _Float16* nb = Nbuf + ((size_t)b * 16 + s) * 4096;
#pragma unroll
  for (int tile = 0; tile < 4; ++tile) {
    const int col = tile * 16 + n16;
#pragma unroll
    for (int kf = 0; kf < 2; ++kf)
      *(half8_t*)(nb + (size_t)col * 64 + kf * 32 + quad * 8) = pb[tile][kf];
  }
  if (lane == 0) lzbuf[b * 16 + s] = lz2;
}

// ---------------------------------------------------------------- merge: w <- P_s w, then alpha0 dot
__global__ __launch_bounds__(64) void merge_kernel(const _Float16* __restrict__ Nbuf,
                                                   const float* __restrict__ lzbuf,
                                                   const float* __restrict__ em,
                                                   const float* __restrict__ start_trans,
                                                   const float* __restrict__ end_trans,
                                                   float* __restrict__ denom) {
  const int b = blockIdx.x, m = threadIdx.x;
  __shared__ float w[64];
  float L2 = 0.f;
  w[m] = fast_exp(end_trans[m]);
  for (int s = 15; s >= 0; --s) {
    lds_fence();
    const _Float16* row = Nbuf + (((size_t)b * 16 + s) * 64 + m) * 64;
    float acc = 0.f;
#pragma unroll
    for (int kf = 0; kf < 8; ++kf) {
      const half8_t rv = *(const half8_t*)(row + kf * 8);
#pragma unroll
      for (int i = 0; i < 8; ++i) acc += (float)rv[i] * w[kf * 8 + i];
    }
    float mx = acc;
#pragma unroll
    for (int off = 32; off > 0; off >>= 1) mx = fmaxf(mx, __shfl_xor(mx, off, 64));
    L2 += __builtin_amdgcn_logf(mx) + lzbuf[b * 16 + s];
    const float inv = __builtin_amdgcn_rcpf(mx);
    lds_fence();
    w[m] = acc * inv;
  }
  lds_fence();
  const float sv = start_trans[m] + em[(size_t)b * NTAG + m];  // t=0 row
  float m0 = sv;
#pragma unroll
  for (int off = 32; off > 0; off >>= 1) m0 = fmaxf(m0, __shfl_xor(m0, off, 64));
  float z = fast_exp(sv - m0) * w[m];
#pragma unroll
  for (int off = 32; off > 0; off >>= 1) z += __shfl_xor(z, off, 64);
  if (m == 0)
    denom[b] = m0 + 0.693147180559945f * (L2 + 6138.0f + __builtin_amdgcn_logf(z));
}

// ---------------------------------------------------------------- final: reduce (denom - num)
__global__ __launch_bounds__(128) void final_kernel(const float* __restrict__ denom,
                                                    const float* __restrict__ num,
                                                    float* __restrict__ out) {
  const int tid = threadIdx.x;
  float v = denom[tid] - num[tid];
#pragma unroll
  for (int off = 32; off > 0; off >>= 1) v += __shfl_xor(v, off, 64);
  __shared__ float red[2];
  if ((tid & 63) == 0) red[tid >> 6] = v;
  __syncthreads();
  if (tid == 0) out[0] = red[0] + red[1];
}

extern "C" void kernel_launch(void* const* d_in, const int* in_sizes, int n_in,
                              void* d_out, int out_size, void* d_ws, size_t ws_size,
                              hipStream_t stream) {
  const int* kmers = (const int*)d_in[0];
  const int* tags = (const int*)d_in[1];
  const float* emb = (const float*)d_in[2];
  const float* w_ih_f = (const float*)d_in[3];
  const float* w_hh_f = (const float*)d_in[4];
  const float* b_ih_f = (const float*)d_in[5];
  const float* b_hh_f = (const float*)d_in[6];
  const float* w_ih_b = (const float*)d_in[7];
  const float* w_hh_b = (const float*)d_in[8];
  const float* b_ih_b = (const float*)d_in[9];
  const float* b_hh_b = (const float*)d_in[10];
  const float* w_proj = (const float*)d_in[11];
  const float* b_proj = (const float*)d_in[12];
  const float* start_trans = (const float*)d_in[13];
  const float* end_trans = (const float*)d_in[14];
  const float* trans = (const float*)d_in[15];

  char* ws = (char*)d_ws;
  half4_t* x = (half4_t*)ws;                       // [0, 33.5M); em aliases after xg done
  _Float16* h_cat = (_Float16*)(ws + 33554432);    // [33.5M, 100.7M)
  float* em = (float*)ws;
  float* out = (float*)d_out;
  // post-emis overlays of the dead h_cat region (path-independent):
  _Float16* Nbuf = (_Float16*)(ws + 33554432);            // 16.8 MB
  float* lzbuf = (float*)(ws + 33554432 + 16777216);      // 8 KB
  float* denom = (float*)(ws + 33554432 + 16785408);      // 512 B
  float* num = (float*)(ws + 33554432 + 16785920);        // 512 B

  const bool fused = ws_size >= 235078656ull;
  if (fused) {
    const int Tseg = 256;
    _Float16* buf0 = (_Float16*)(ws + 100663296);              // 64 MB
    _Float16* buf1 = (_Float16*)(ws + 100663296 + 67108864);   // 64 MB
    _Float16* expem = (_Float16*)(ws + 100663296);             // aliases buf0 (dead after lstm)
    _Float16* h_state = (_Float16*)(ws + 100663296 + 134217728);
    float* c_state = (float*)(ws + 100663296 + 134217728 + 65536);

    hipLaunchKernelGGL(initembed_kernel, dim3(16432), dim3(256), 0, stream, kmers, emb, x,
                       (float4_t*)h_state);
    hipLaunchKernelGGL(xg_kernel, dim3(Tseg), dim3(512), 0, stream, (const _Float16*)x,
                       w_ih_f, b_ih_f, b_hh_f, w_ih_b, b_ih_b, b_hh_b, buf0, 0, Tseg);
    for (int s = 0; s < 3; ++s) {
      _Float16* rd = (s & 1) ? buf1 : buf0;
      _Float16* wr = (s & 1) ? buf0 : buf1;
      hipLaunchKernelGGL(lstm_xg_kernel, dim3(8 + Tseg / 2), dim3(1024), 0, stream,
                         (const _Float16*)rd, wr, (const _Float16*)x, w_hh_f, w_hh_b,
                         w_ih_f, b_ih_f, b_hh_f, w_ih_b, b_ih_b, b_hh_b,
                         h_cat, h_state, c_state, s, s + 1, Tseg);
    }
    hipLaunchKernelGGL(lstm_xg_kernel, dim3(8), dim3(1024), 0, stream,
                       (const _Float16*)buf1, buf0, (const _Float16*)x, w_hh_f, w_hh_b,
                       w_ih_f, b_ih_f, b_hh_f, w_ih_b, b_ih_b, b_hh_b,
                       h_cat, h_state, c_state, 3, 0, Tseg);
    hipLaunchKernelGGL(emis_kernel, dim3(2048), dim3(256), 0, stream, h_cat, w_proj, b_proj, em,
                       expem);
    hipLaunchKernelGGL(mcrf_kernel, dim3(2176), dim3(64), 0, stream, em,
                       (const _Float16*)expem, trans, tags, start_trans, end_trans, Nbuf, lzbuf,
                       num);
    hipLaunchKernelGGL(merge_kernel, dim3(128), dim3(64), 0, stream, (const _Float16*)Nbuf,
                       lzbuf, em, start_trans, end_trans, denom);
    hipLaunchKernelGGL(final_kernel, dim3(1), dim3(128), 0, stream, denom, num, out);
  } else {
    int nseg;
    if (ws_size >= 167969792ull) nseg = 4;
    else if (ws_size >= 134415360ull) nseg = 8;
    else nseg = 16;
    const int Tseg = TT / nseg;
    const size_t xg_bytes = 268435456ull / (size_t)nseg;
    _Float16* xgbuf = (_Float16*)(ws + 100663296);
    _Float16* expem = (_Float16*)(ws + 100663296);
    _Float16* h_state = (_Float16*)(ws + 100663296 + xg_bytes);
    float* c_state = (float*)(ws + 100663296 + xg_bytes + 65536);

    hipLaunchKernelGGL(initembed_kernel, dim3(16432), dim3(256), 0, stream, kmers, emb, x,
                       (float4_t*)h_state);
    for (int s = 0; s < nseg; ++s) {
      hipLaunchKernelGGL(xg_kernel, dim3(Tseg), dim3(512), 0, stream, (const _Float16*)x,
                         w_ih_f, b_ih_f, b_hh_f, w_ih_b, b_ih_b, b_hh_b, xgbuf, s, Tseg);
      hipLaunchKernelGGL(lstm_xg_kernel, dim3(8), dim3(1024), 0, stream,
                         (const _Float16*)xgbuf, xgbuf, (const _Float16*)x, w_hh_f, w_hh_b,
                         w_ih_f, b_ih_f, b_hh_f, w_ih_b, b_ih_b, b_hh_b,
                         h_cat, h_state, c_state, s, s, Tseg);
    }
    hipLaunchKernelGGL(emis_kernel, dim3(2048), dim3(256), 0, stream, h_cat, w_proj, b_proj, em,
                       expem);
    hipLaunchKernelGGL(mcrf_kernel, dim3(2176), dim3(64), 0, stream, em,
                       (const _Float16*)expem, trans, tags, start_trans, end_trans, Nbuf, lzbuf,
                       num);
    hipLaunchKernelGGL(merge_kernel, dim3(128), dim3(64), 0, stream, (const _Float16*)Nbuf,
                       lzbuf, em, start_trans, end_trans, denom);
    hipLaunchKernelGGL(final_kernel, dim3(1), dim3(128), 0, stream, denom, num, out);
  }
}

// Round 9
// 3161.281 us; speedup vs baseline: 1.0011x; 1.0011x over previous
//
#include <hip/hip_runtime.h>
#include <hip/hip_bf16.h>

typedef _Float16 half8_t __attribute__((ext_vector_type(8)));
typedef _Float16 half4_t __attribute__((ext_vector_type(4)));
typedef _Float16 half2_t __attribute__((ext_vector_type(2)));
typedef float float4_t __attribute__((ext_vector_type(4)));
typedef unsigned int uint2_t __attribute__((ext_vector_type(2)));

#define TT 1024
#define BB 128
#define EE 128
#define HH 128
#define NTAG 64
#define ASTR 144  // [batch][hu] LDS panel stride (f16) — R6-proven for the b128 read pattern

__device__ __forceinline__ float fast_exp(float x) {
  return __builtin_amdgcn_exp2f(x * 1.44269504088896f);
}
// LDS-only barrier: does NOT drain vmcnt -> global loads/stores stay in flight.
__device__ __forceinline__ void lds_barrier() {
  asm volatile("s_waitcnt lgkmcnt(0)\n\ts_barrier" ::: "memory");
}
// Single-wave LDS write->read fence.
__device__ __forceinline__ void lds_fence() {
  asm volatile("s_waitcnt lgkmcnt(0)" ::: "memory");
}
__device__ __forceinline__ half2_t cvt_pk(float a, float b) {
  return __builtin_bit_cast(half2_t, __builtin_amdgcn_cvt_pkrtz(a, b));
}
__device__ __forceinline__ half2_t h2bc(float v) {
  _Float16 h = (_Float16)v;
  half2_t r; r[0] = h; r[1] = h;
  return r;
}
__device__ __forceinline__ half8_t h8bc(float v) {
  _Float16 h = (_Float16)v;
  half8_t r;
#pragma unroll
  for (int i = 0; i < 8; ++i) r[i] = h;
  return r;
}
// max over the 4 quads (lane bits 4,5) for each n16 column — pure VALU (permlane swaps)
__device__ __forceinline__ float quad_max4(float v) {
  unsigned a = __builtin_bit_cast(unsigned, v);
  uint2_t r = __builtin_amdgcn_permlane32_swap(a, a, false, false);
  float m = fmaxf(__builtin_bit_cast(float, r[0]), __builtin_bit_cast(float, r[1]));
  unsigned b = __builtin_bit_cast(unsigned, m);
  uint2_t s = __builtin_amdgcn_permlane16_swap(b, b, false, false);
  return fmaxf(__builtin_bit_cast(float, s[0]), __builtin_bit_cast(float, s[1]));
}
// deg-5 odd tanh poly (fit at 1, 1.6; clamp +-1.6): 6 pk instrs
__device__ __forceinline__ half2_t tanh6(half2_t x) {
  half2_t y = __builtin_elementwise_min(__builtin_elementwise_max(x, h2bc(-1.6f)), h2bc(1.6f));
  half2_t u = y * y;
  half2_t p = u * h2bc(0.04667f) + h2bc(-0.28507f);
  p = u * p + h2bc(1.0f);
  return y * p;
}
// sigmoid, x/2 folded into coefficients: 6 pk instrs
__device__ __forceinline__ half2_t sig6(half2_t x) {
  half2_t y = __builtin_elementwise_min(__builtin_elementwise_max(x, h2bc(-3.2f)), h2bc(3.2f));
  half2_t u = y * y;
  half2_t q = u * h2bc(0.00072921875f) + h2bc(-0.017816875f);
  q = u * q + h2bc(0.25f);
  return y * q + h2bc(0.5f);
}

// ---------------------------------------------------------------- init + embed (fused, independent)
__global__ __launch_bounds__(256) void initembed_kernel(const int* __restrict__ kmers,
                                                        const float* __restrict__ emb,
                                                        half4_t* __restrict__ x,
                                                        float4_t* __restrict__ state) {
  if (blockIdx.x < 48) {
    state[blockIdx.x * 256 + threadIdx.x] = (float4_t){0.f, 0.f, 0.f, 0.f};
    return;
  }
  const int g = (blockIdx.x - 48) * 256 + threadIdx.x;
  const int row = g >> 5, seg = g & 31;
  const int km = kmers[row];
  const float4_t v = ((const float4_t*)(emb + (size_t)km * EE))[seg];
  half4_t o;
  o[0] = (_Float16)v[0]; o[1] = (_Float16)v[1];
  o[2] = (_Float16)v[2]; o[3] = (_Float16)v[3];
  x[(size_t)row * 32 + seg] = o;
}

// ---------------------------------------------------------------- xg body (device)
// Orientation: A = W_ih (regs), B = x^T (b128 global loads), C rows=hu-part, col=batch.
__device__ __forceinline__ void xg_body(
    int wg, int tid, const _Float16* __restrict__ x,
    const float* __restrict__ w_ih_f, const float* __restrict__ b_ih_f, const float* __restrict__ b_hh_f,
    const float* __restrict__ w_ih_b, const float* __restrict__ b_ih_b, const float* __restrict__ b_hh_b,
    _Float16* __restrict__ xgbuf, int s, int Tseg) {
  const int nt = Tseg >> 4;
  const int dir = wg / (8 * nt);
  const int rem = wg - dir * 8 * nt;
  const int chunk = rem / nt;
  const int tb = rem - chunk * nt;
  const int wave = tid >> 6, lane = tid & 63;
  const int n16 = lane & 15, quad = lane >> 4;

  const float* wih = dir ? w_ih_b : w_ih_f;
  const float* bih = dir ? b_ih_b : b_ih_f;
  const float* bhh = dir ? b_hh_b : b_hh_f;

  half8_t wf[4][4];
#pragma unroll
  for (int g = 0; g < 4; ++g) {
    const int row = g * HH + wave * 16 + n16;
#pragma unroll
    for (int kf = 0; kf < 4; ++kf) {
      const float* src = wih + row * EE + kf * 32 + quad * 8;
#pragma unroll
      for (int i = 0; i < 8; ++i) wf[g][kf][i] = (_Float16)src[i];
    }
  }
  float4_t bias4[4];
#pragma unroll
  for (int g = 0; g < 4; ++g) {
    const int row = g * HH + wave * 16 + quad * 4;
    const float4_t bi = *(const float4_t*)(bih + row);
    const float4_t bh = *(const float4_t*)(bhh + row);
    bias4[g] = bi + bh;
  }

  const int l0 = tb * 16;
  half8_t xb[4];
  {
    const int te = dir ? (TT - 1 - (s * Tseg + l0)) : (s * Tseg + l0);
#pragma unroll
    for (int kf = 0; kf < 4; ++kf)
      xb[kf] = *(const half8_t*)(x + ((size_t)te * BB + chunk * 16 + n16) * EE + kf * 32 + quad * 8);
  }
  for (int u = 0; u < 16; ++u) {
    const int l = l0 + u;
    half8_t xn[4] = {};
    if (u < 15) {
      const int tn = dir ? (TT - 1 - (s * Tseg + l + 1)) : (s * Tseg + l + 1);
#pragma unroll
      for (int kf = 0; kf < 4; ++kf)
        xn[kf] = *(const half8_t*)(x + ((size_t)tn * BB + chunk * 16 + n16) * EE + kf * 32 + quad * 8);
    }
    float4_t acc[4];
#pragma unroll
    for (int g = 0; g < 4; ++g) acc[g] = bias4[g];
#pragma unroll
    for (int kf = 0; kf < 4; ++kf)
#pragma unroll
      for (int g = 0; g < 4; ++g)
        acc[g] = __builtin_amdgcn_mfma_f32_16x16x32_f16(wf[g][kf], xb[kf], acc[g], 0, 0, 0);
    half8_t ho0, ho1;
#pragma unroll
    for (int r = 0; r < 4; ++r) {
      ho0[r] = (_Float16)acc[0][r];
      ho0[4 + r] = (_Float16)acc[1][r];
      ho1[r] = (_Float16)acc[2][r];
      ho1[4 + r] = (_Float16)acc[3][r];
    }
    _Float16* ob = xgbuf + (size_t)dir * Tseg * 65536 + (size_t)l * 65536 + chunk * 8192 +
                   wave * 1024 + lane * 16;
    *(half8_t*)ob = ho0;
    *(half8_t*)(ob + 8) = ho1;
#pragma unroll
    for (int kf = 0; kf < 4; ++kf) xb[kf] = xn[kf];
  }
}

// ---------------------------------------------------------------- standalone xg (first segment)
__global__ __launch_bounds__(512) void xg_kernel(
    const _Float16* __restrict__ x,
    const float* __restrict__ w_ih_f, const float* __restrict__ b_ih_f, const float* __restrict__ b_hh_f,
    const float* __restrict__ w_ih_b, const float* __restrict__ b_ih_b, const float* __restrict__ b_hh_b,
    _Float16* __restrict__ xgbuf, int s, int Tseg) {
  xg_body(blockIdx.x, threadIdx.x, x, w_ih_f, b_ih_f, b_hh_f, w_ih_b, b_ih_b, b_hh_b, xgbuf, s,
          Tseg);
}

// ---------------------------------------------------------------- fused: lstm(s) both dirs + xg(s+1)
// Blocks 0..7: ONE chunk each, BOTH direction chains in one 16-wave block (dir = wave>>3).
// Wave->SIMD round-robin puts 2 fwd + 2 bwd waves per SIMD: two INDEPENDENT dependency
// chains per SIMD, so one chain's LDS/MFMA/epilogue stalls are filled by the other.
// __launch_bounds__(1024, 1): R8's (1024,4) still produced VGPR=64 + spills (FETCH/WRITE
// +110MB scratch) — under a CUDA-style "min blocks" reading, 4 blocks x 16 waves = 16 w/EU
// -> clamp 8 -> cap 64. Arg=1 gives cap 128 under EITHER reading (1 block x 16 waves = 4
// w/EU -> 128; or 1 wave/EU -> 512, clamped to 128 by 1024-thread launchability). At
// VGPR>=85, 16-wave blocks leave <16 wave slots -> 1 block/CU, so xg can't steal slots.
// Blocks >= 8: TWO xg units per 1024-thread block.
__global__ __launch_bounds__(1024, 1) void lstm_xg_kernel(
    const _Float16* __restrict__ xgrd, _Float16* __restrict__ xgwr,
    const _Float16* __restrict__ x,
    const float* __restrict__ w_hh_f, const float* __restrict__ w_hh_b,
    const float* __restrict__ w_ih_f, const float* __restrict__ b_ih_f, const float* __restrict__ b_hh_f,
    const float* __restrict__ w_ih_b, const float* __restrict__ b_ih_b, const float* __restrict__ b_hh_b,
    _Float16* __restrict__ h_cat, _Float16* __restrict__ h_state, float* __restrict__ c_state,
    int s, int sx, int Tseg) {
  __shared__ _Float16 A[2][2][16 * ASTR];  // [dir][buf][panel]

  if (blockIdx.x >= 8) {
    const int unit = (blockIdx.x - 8) * 2 + (threadIdx.x >> 9);
    xg_body(unit, threadIdx.x & 511, x, w_ih_f, b_ih_f, b_hh_f, w_ih_b, b_ih_b, b_hh_b, xgwr,
            sx, Tseg);
    return;
  }
  const int chunk = blockIdx.x;
  const int b0 = chunk * 16;
  const int tid = threadIdx.x;
  const int wave16 = tid >> 6, lane = tid & 63;
  const int dir = wave16 >> 3, w = wave16 & 7;
  const int n16 = lane & 15, quad = lane >> 4;
  const float* w_hh = dir ? w_hh_b : w_hh_f;

  half8_t wf[4][4];
#pragma unroll
  for (int g = 0; g < 4; ++g) {
    const int row = g * HH + w * 16 + n16;
#pragma unroll
    for (int kf = 0; kf < 4; ++kf) {
      const float* src = w_hh + row * HH + kf * 32 + quad * 8;
#pragma unroll
      for (int i = 0; i < 8; ++i) wf[g][kf][i] = (_Float16)src[i];
    }
  }
  // persistent state: layout identical to R5 ((dir*8+chunk)*8+w)
  const int sidx = (((dir * 8 + chunk) * 8 + w) * 64 + lane) * 4;
  half4_t h4 = *(const half4_t*)(h_state + sidx);
  float4_t c4 = *(const float4_t*)(c_state + sidx);
  half2_t c2[2];
  c2[0] = cvt_pk(c4[0], c4[1]);
  c2[1] = cvt_pk(c4[2], c4[3]);
  *(half4_t*)(&A[dir][0][n16 * ASTR + w * 16 + quad * 4]) = h4;  // seed h_{-1}

  const _Float16* xgw =
      xgrd + (size_t)dir * Tseg * 65536 + chunk * 8192 + w * 1024 + (size_t)lane * 16;
  half4_t hlast = h4;
  const float4_t z4 = {0.f, 0.f, 0.f, 0.f};
  const int te0 = dir ? (TT - 1 - s * Tseg) : (s * Tseg);
  _Float16* gp_run = h_cat + ((size_t)te0 * BB + b0 + n16) * 256 + dir * HH + w * 16 + quad * 4;
  const ptrdiff_t dstep = dir ? -(ptrdiff_t)32768 : (ptrdiff_t)32768;

  half8_t pf0[4], pf1[4];
#pragma unroll
  for (int j = 0; j < 4; ++j) {
    const _Float16* p = xgw + (size_t)j * 65536;
    pf0[j] = *(const half8_t*)p;
    pf1[j] = *(const half8_t*)(p + 8);
  }
  _Float16* const Ad0 = &A[dir][0][0];
  _Float16* const Ad1 = &A[dir][1][0];

#define LSTM_STEP(AB, AN, X0, X1)                                                          \
  {                                                                                        \
    const _Float16* Abp = AB;                                                              \
    _Float16* Anp = AN;                                                                    \
    half8_t hb0 = *(const half8_t*)(Abp + n16 * ASTR + 0 * 32 + quad * 8);                 \
    half8_t hb1 = *(const half8_t*)(Abp + n16 * ASTR + 1 * 32 + quad * 8);                 \
    half8_t hb2 = *(const half8_t*)(Abp + n16 * ASTR + 2 * 32 + quad * 8);                 \
    half8_t hb3 = *(const half8_t*)(Abp + n16 * ASTR + 3 * 32 + quad * 8);                 \
    float4_t acc[4];                                                                       \
    _Pragma("unroll") for (int g = 0; g < 4; ++g) {                                        \
      acc[g] = __builtin_amdgcn_mfma_f32_16x16x32_f16(wf[g][0], hb0, z4, 0, 0, 0);         \
    }                                                                                      \
    _Pragma("unroll") for (int g = 0; g < 4; ++g) {                                        \
      acc[g] = __builtin_amdgcn_mfma_f32_16x16x32_f16(wf[g][1], hb1, acc[g], 0, 0, 0);     \
    }                                                                                      \
    _Pragma("unroll") for (int g = 0; g < 4; ++g) {                                        \
      acc[g] = __builtin_amdgcn_mfma_f32_16x16x32_f16(wf[g][2], hb2, acc[g], 0, 0, 0);     \
    }                                                                                      \
    _Pragma("unroll") for (int g = 0; g < 4; ++g) {                                        \
      acc[g] = __builtin_amdgcn_mfma_f32_16x16x32_f16(wf[g][3], hb3, acc[g], 0, 0, 0);     \
    }                                                                                      \
    const half2_t* x0p = (const half2_t*)&X0;                                              \
    const half2_t* x1p = (const half2_t*)&X1;                                              \
    half4_t hstore;                                                                        \
    _Pragma("unroll") for (int p = 0; p < 2; ++p) {                                        \
      const half2_t i_ = sig6(cvt_pk(acc[0][2 * p], acc[0][2 * p + 1]) + x0p[p]);          \
      const half2_t f_ = sig6(cvt_pk(acc[1][2 * p], acc[1][2 * p + 1]) + x0p[2 + p]);      \
      const half2_t g_ = tanh6(cvt_pk(acc[2][2 * p], acc[2][2 * p + 1]) + x1p[p]);         \
      const half2_t o_ = sig6(cvt_pk(acc[3][2 * p], acc[3][2 * p + 1]) + x1p[2 + p]);      \
      c2[p] = f_ * c2[p] + i_ * g_;                                                        \
      const half2_t hh = o_ * tanh6(c2[p]);                                                \
      hstore[2 * p] = hh[0];                                                               \
      hstore[2 * p + 1] = hh[1];                                                           \
    }                                                                                      \
    *(half4_t*)(Anp + n16 * ASTR + w * 16 + quad * 4) = hstore;                            \
    *(half4_t*)gp_run = hstore;                                                            \
    hlast = hstore;                                                                        \
  }

  for (int il = 0; il < Tseg - 4; il += 4) {
#pragma unroll
    for (int j = 0; j < 4; ++j) {
      lds_barrier();
      if (j & 1) {
        LSTM_STEP(Ad1, Ad0, pf0[j], pf1[j]);
      } else {
        LSTM_STEP(Ad0, Ad1, pf0[j], pf1[j]);
      }
      const _Float16* p = xgw + (size_t)(il + j + 4) * 65536;
      pf0[j] = *(const half8_t*)p;
      pf1[j] = *(const half8_t*)(p + 8);
      gp_run += dstep;
    }
  }
#pragma unroll
  for (int j = 0; j < 4; ++j) {
    lds_barrier();
    if (j & 1) {
      LSTM_STEP(Ad1, Ad0, pf0[j], pf1[j]);
    } else {
      LSTM_STEP(Ad0, Ad1, pf0[j], pf1[j]);
    }
    gp_run += dstep;
  }
#undef LSTM_STEP

  *(half4_t*)(h_state + sidx) = hlast;
  c4[0] = (float)c2[0][0]; c4[1] = (float)c2[0][1];
  c4[2] = (float)c2[1][0]; c4[3] = (float)c2[1][1];
  *(float4_t*)(c_state + sidx) = c4;
}

// ---------------------------------------------------------------- emissions: em f32 + expem f16
__global__ __launch_bounds__(256) void emis_kernel(const _Float16* __restrict__ h_cat,
                                                   const float* __restrict__ w_proj,
                                                   const float* __restrict__ b_proj,
                                                   float* __restrict__ em,
                                                   _Float16* __restrict__ expem) {
  const int tid = threadIdx.x;
  const int wave = tid >> 6, lane = tid & 63;
  const int n16 = lane & 15, quad = lane >> 4;
  const size_t row0 = (size_t)blockIdx.x * 64 + wave * 16;

  half8_t bf[4][8];
#pragma unroll
  for (int nt = 0; nt < 4; ++nt) {
    const float* wp = w_proj + (nt * 16 + n16) * 256;
#pragma unroll
    for (int kf = 0; kf < 8; ++kf) {
      const int kb = kf * 32 + quad * 8;
#pragma unroll
      for (int i = 0; i < 8; ++i) bf[nt][kf][i] = (_Float16)wp[kb + i];
    }
  }
  float4_t acc[4];
#pragma unroll
  for (int nt = 0; nt < 4; ++nt) {
    const float bv = b_proj[nt * 16 + n16];
    acc[nt] = (float4_t){bv, bv, bv, bv};
  }
#pragma unroll
  for (int kf = 0; kf < 8; ++kf) {
    half8_t af = *(const half8_t*)(h_cat + (row0 + n16) * 256 + kf * 32 + quad * 8);
#pragma unroll
    for (int nt = 0; nt < 4; ++nt)
      acc[nt] = __builtin_amdgcn_mfma_f32_16x16x32_f16(af, bf[nt][kf], acc[nt], 0, 0, 0);
  }
#pragma unroll
  for (int nt = 0; nt < 4; ++nt)
#pragma unroll
    for (int r = 0; r < 4; ++r) {
      const size_t idx = (row0 + quad * 4 + r) * NTAG + nt * 16 + n16;
      em[idx] = acc[nt][r];
      expem[idx] = (_Float16)fast_exp(acc[nt][r]);
    }
}

// ---------------------------------------------------------------- segment-parallel CRF matrices
// 2048 chains (128 batches x 16 segments), 1 wave each: N <- diag(g_t) (E^T N), N init = I.
// Stored as Nbuf[b][s][c][k] = N[k][c] = P_s[c][k]. Blocks >= 2048: CRF numerator.
__global__ __launch_bounds__(64) void mcrf_kernel(const float* __restrict__ em,
                                                  const _Float16* __restrict__ expem,
                                                  const float* __restrict__ trans,
                                                  const int* __restrict__ tags,
                                                  const float* __restrict__ start_trans,
                                                  const float* __restrict__ end_trans,
                                                  _Float16* __restrict__ Nbuf,
                                                  float* __restrict__ lzbuf,
                                                  float* __restrict__ num) {
  const int lane = threadIdx.x;
  if (blockIdx.x >= 2048) {  // ---------------- numerator (1 wave per batch)
    const int nb = blockIdx.x - 2048;
    const int tg = tags[nb];
    float acc = 0.f;
    for (int t = lane; t < TT; t += 64)
      acc += em[((size_t)t * BB + nb) * NTAG + tg];
#pragma unroll
    for (int off = 32; off > 0; off >>= 1) acc += __shfl_xor(acc, off, 64);
    if (lane == 0)
      num[nb] = start_trans[tg] + end_trans[tg] + 1023.0f * trans[tg * NTAG + tg] + acc;
    return;
  }
  const int n16 = lane & 15, quad = lane >> 4;
  const int b = blockIdx.x >> 4;
  const int s = blockIdx.x & 15;

  half8_t efA[4][2];
#pragma unroll
  for (int mt = 0; mt < 4; ++mt)
#pragma unroll
    for (int kf = 0; kf < 2; ++kf)
#pragma unroll
      for (int i = 0; i < 8; ++i) {
        const int m = mt * 16 + n16, k = kf * 32 + quad * 8 + i;
        efA[mt][kf][i] = (_Float16)(fast_exp(trans[k * NTAG + m]) * 0.015625f);
      }

  half8_t pb[4][2];
#pragma unroll
  for (int tile = 0; tile < 4; ++tile)
#pragma unroll
    for (int kf = 0; kf < 2; ++kf)
#pragma unroll
      for (int i = 0; i < 8; ++i) {
        const int k = kf * 32 + quad * 8 + i;
        pb[tile][kf][i] = (_Float16)((k == tile * 16 + n16) ? 1.f : 0.f);
      }

  float lz2 = 0.f;
  const float4_t z4 = {0.f, 0.f, 0.f, 0.f};
  const _Float16* exb = expem + (size_t)b * NTAG;
  const int t0 = s * 64 + 1;
  const int nsteps = (s == 15) ? 63 : 64;

#define MCRF_CORE(PB0, PB1, NB0, NB1)                                                      \
  {                                                                                        \
    float4_t a0 = __builtin_amdgcn_mfma_f32_16x16x32_f16(efA[0][0], PB0, z4, 0, 0, 0);     \
    float4_t a1 = __builtin_amdgcn_mfma_f32_16x16x32_f16(efA[1][0], PB0, z4, 0, 0, 0);     \
    float4_t a2 = __builtin_amdgcn_mfma_f32_16x16x32_f16(efA[2][0], PB0, z4, 0, 0, 0);     \
    float4_t a3 = __builtin_amdgcn_mfma_f32_16x16x32_f16(efA[3][0], PB0, z4, 0, 0, 0);     \
    a0 = __builtin_amdgcn_mfma_f32_16x16x32_f16(efA[0][1], PB1, a0, 0, 0, 0);              \
    a1 = __builtin_amdgcn_mfma_f32_16x16x32_f16(efA[1][1], PB1, a1, 0, 0, 0);              \
    a2 = __builtin_amdgcn_mfma_f32_16x16x32_f16(efA[2][1], PB1, a2, 0, 0, 0);              \
    a3 = __builtin_amdgcn_mfma_f32_16x16x32_f16(efA[3][1], PB1, a3, 0, 0, 0);              \
    half2_t dpk[4][2];                                                                     \
    dpk[0][0] = cvt_pk(a0[0], a0[1]); dpk[0][1] = cvt_pk(a0[2], a0[3]);                    \
    dpk[1][0] = cvt_pk(a1[0], a1[1]); dpk[1][1] = cvt_pk(a1[2], a1[3]);                    \
    dpk[2][0] = cvt_pk(a2[0], a2[1]); dpk[2][1] = cvt_pk(a2[2], a2[3]);                    \
    dpk[3][0] = cvt_pk(a3[0], a3[1]); dpk[3][1] = cvt_pk(a3[2], a3[3]);                    \
    half2_t* wwp0 = (half2_t*)&NB0;                                                        \
    half2_t* wwp1 = (half2_t*)&NB1;                                                        \
    _Pragma("unroll") for (int kf = 0; kf < 2; ++kf) {                                     \
      half2_t* wp = kf ? wwp1 : wwp0;                                                      \
      _Pragma("unroll") for (int p = 0; p < 2; ++p) {                                      \
        const unsigned Xu = __builtin_bit_cast(unsigned, dpk[2 * kf][p]);                  \
        const unsigned Yu = __builtin_bit_cast(unsigned, dpk[2 * kf + 1][p]);              \
        uint2_t r1 = __builtin_amdgcn_permlane32_swap(Xu, Yu, false, false);               \
        uint2_t r2 = __builtin_amdgcn_permlane16_swap(r1[0], r1[1], false, false);         \
        wp[p] = __builtin_bit_cast(half2_t, r2[0]);                                        \
        wp[2 + p] = __builtin_bit_cast(half2_t, r2[1]);                                    \
      }                                                                                    \
    }                                                                                      \
  }

#define MSTEP(GC0, GC1, IT)                                                                \
  {                                                                                        \
    _Pragma("unroll") for (int tile = 0; tile < 4; ++tile) {                               \
      half8_t nb0, nb1;                                                                    \
      MCRF_CORE(pb[tile][0], pb[tile][1], nb0, nb1)                                        \
      pb[tile][0] = nb0 * GC0;                                                             \
      pb[tile][1] = nb1 * GC1;                                                             \
    }                                                                                      \
    if (((IT) & 15) == 15) {                                                               \
      half8_t m8 = __builtin_elementwise_max(pb[0][0], pb[0][1]);                          \
      m8 = __builtin_elementwise_max(m8, __builtin_elementwise_max(pb[1][0], pb[1][1]));   \
      m8 = __builtin_elementwise_max(m8, __builtin_elementwise_max(pb[2][0], pb[2][1]));   \
      m8 = __builtin_elementwise_max(m8, __builtin_elementwise_max(pb[3][0], pb[3][1]));   \
      float mm = (float)m8[0];                                                             \
      _Pragma("unroll") for (int i = 1; i < 8; ++i) mm = fmaxf(mm, (float)m8[i]);          \
      mm = quad_max4(mm);                                                                  \
      mm = fmaxf(mm, __shfl_xor(mm, 1, 64));                                               \
      mm = fmaxf(mm, __shfl_xor(mm, 2, 64));                                               \
      mm = fmaxf(mm, __shfl_xor(mm, 4, 64));                                               \
      mm = fmaxf(mm, __shfl_xor(mm, 8, 64));                                               \
      lz2 += __builtin_amdgcn_logf(mm);                                                    \
      const half8_t rc8 = h8bc(__builtin_amdgcn_rcpf(mm));                                 \
      _Pragma("unroll") for (int tile = 0; tile < 4; ++tile) {                             \
        pb[tile][0] *= rc8;                                                                \
        pb[tile][1] *= rc8;                                                                \
      }                                                                                    \
    }                                                                                      \
  }

  half8_t pre0[4], pre1[4];
#pragma unroll
  for (int j = 0; j < 4; ++j) {
    const size_t tt = (size_t)(t0 + j) * 8192;
    pre0[j] = *(const half8_t*)(exb + tt + quad * 8);
    pre1[j] = *(const half8_t*)(exb + tt + 32 + quad * 8);
  }
  int it = 0;
  const int full4 = nsteps >> 2;
  for (int grp = 0; grp < full4; ++grp) {
#pragma unroll
    for (int j = 0; j < 4; ++j) {
      const half8_t gc0 = pre0[j], gc1 = pre1[j];
      int tf = t0 + it + 4;
      tf = tf > 1023 ? 1023 : tf;
      const size_t tt = (size_t)tf * 8192;
      pre0[j] = *(const half8_t*)(exb + tt + quad * 8);
      pre1[j] = *(const half8_t*)(exb + tt + 32 + quad * 8);
      MSTEP(gc0, gc1, it)
      ++it;
    }
  }
  for (; it < nsteps; ++it) {
    const size_t tt = (size_t)(t0 + it) * 8192;
    const half8_t gc0 = *(const half8_t*)(exb + tt + quad * 8);
    const half8_t gc1 = *(const half8_t*)(exb + tt + 32 + quad * 8);
    MSTEP(gc0, gc1, it)
  }
#undef MSTEP
#undef MCRF_CORE

  _Float16* nb = Nbuf + ((size_t)b * 16 + s) * 4096;
#pragma unroll
  for (int tile = 0; tile < 4; ++tile) {
    const int col = tile * 16 + n16;
#pragma unroll
    for (int kf = 0; kf < 2; ++kf)
      *(half8_t*)(nb + (size_t)col * 64 + kf * 32 + quad * 8) = pb[tile][kf];
  }
  if (lane == 0) lzbuf[b * 16 + s] = lz2;
}

// ---------------------------------------------------------------- merge: w <- P_s w, then alpha0 dot
__global__ __launch_bounds__(64) void merge_kernel(const _Float16* __restrict__ Nbuf,
                                                   const float* __restrict__ lzbuf,
                                                   const float* __restrict__ em,
                                                   const float* __restrict__ start_trans,
                                                   const float* __restrict__ end_trans,
                                                   float* __restrict__ denom) {
  const int b = blockIdx.x, m = threadIdx.x;
  __shared__ float w[64];
  float L2 = 0.f;
  w[m] = fast_exp(end_trans[m]);
  for (int s = 15; s >= 0; --s) {
    lds_fence();
    const _Float16* row = Nbuf + (((size_t)b * 16 + s) * 64 + m) * 64;
    float acc = 0.f;
#pragma unroll
    for (int kf = 0; kf < 8; ++kf) {
      const half8_t rv = *(const half8_t*)(row + kf * 8);
#pragma unroll
      for (int i = 0; i < 8; ++i) acc += (float)rv[i] * w[kf * 8 + i];
    }
    float mx = acc;
#pragma unroll
    for (int off = 32; off > 0; off >>= 1) mx = fmaxf(mx, __shfl_xor(mx, off, 64));
    L2 += __builtin_amdgcn_logf(mx) + lzbuf[b * 16 + s];
    const float inv = __builtin_amdgcn_rcpf(mx);
    lds_fence();
    w[m] = acc * inv;
  }
  lds_fence();
  const float sv = start_trans[m] + em[(size_t)b * NTAG + m];  // t=0 row
  float m0 = sv;
#pragma unroll
  for (int off = 32; off > 0; off >>= 1) m0 = fmaxf(m0, __shfl_xor(m0, off, 64));
  float z = fast_exp(sv - m0) * w[m];
#pragma unroll
  for (int off = 32; off > 0; off >>= 1) z += __shfl_xor(z, off, 64);
  if (m == 0)
    denom[b] = m0 + 0.693147180559945f * (L2 + 6138.0f + __builtin_amdgcn_logf(z));
}

// ---------------------------------------------------------------- final: reduce (denom - num)
__global__ __launch_bounds__(128) void final_kernel(const float* __restrict__ denom,
                                                    const float* __restrict__ num,
                                                    float* __restrict__ out) {
  const int tid = threadIdx.x;
  float v = denom[tid] - num[tid];
#pragma unroll
  for (int off = 32; off > 0; off >>= 1) v += __shfl_xor(v, off, 64);
  __shared__ float red[2];
  if ((tid & 63) == 0) red[tid >> 6] = v;
  __syncthreads();
  if (tid == 0) out[0] = red[0] + red[1];
}

extern "C" void kernel_launch(void* const* d_in, const int* in_sizes, int n_in,
                              void* d_out, int out_size, void* d_ws, size_t ws_size,
                              hipStream_t stream) {
  const int* kmers = (const int*)d_in[0];
  const int* tags = (const int*)d_in[1];
  const float* emb = (const float*)d_in[2];
  const float* w_ih_f = (const float*)d_in[3];
  const float* w_hh_f = (const float*)d_in[4];
  const float* b_ih_f = (const float*)d_in[5];
  const float* b_hh_f = (const float*)d_in[6];
  const float* w_ih_b = (const float*)d_in[7];
  const float* w_hh_b = (const float*)d_in[8];
  const float* b_ih_b = (const float*)d_in[9];
  const float* b_hh_b = (const float*)d_in[10];
  const float* w_proj = (const float*)d_in[11];
  const float* b_proj = (const float*)d_in[12];
  const float* start_trans = (const float*)d_in[13];
  const float* end_trans = (const float*)d_in[14];
  const float* trans = (const float*)d_in[15];

  char* ws = (char*)d_ws;
  half4_t* x = (half4_t*)ws;                       // [0, 33.5M); em aliases after xg done
  _Float16* h_cat = (_Float16*)(ws + 33554432);    // [33.5M, 100.7M)
  float* em = (float*)ws;
  float* out = (float*)d_out;
  // post-emis overlays of the dead h_cat region (path-independent):
  _Float16* Nbuf = (_Float16*)(ws + 33554432);            // 16.8 MB
  float* lzbuf = (float*)(ws + 33554432 + 16777216);      // 8 KB
  float* denom = (float*)(ws + 33554432 + 16785408);      // 512 B
  float* num = (float*)(ws + 33554432 + 16785920);        // 512 B

  const bool fused = ws_size >= 235078656ull;
  if (fused) {
    const int Tseg = 256;
    _Float16* buf0 = (_Float16*)(ws + 100663296);              // 64 MB
    _Float16* buf1 = (_Float16*)(ws + 100663296 + 67108864);   // 64 MB
    _Float16* expem = (_Float16*)(ws + 100663296);             // aliases buf0 (dead after lstm)
    _Float16* h_state = (_Float16*)(ws + 100663296 + 134217728);
    float* c_state = (float*)(ws + 100663296 + 134217728 + 65536);

    hipLaunchKernelGGL(initembed_kernel, dim3(16432), dim3(256), 0, stream, kmers, emb, x,
                       (float4_t*)h_state);
    hipLaunchKernelGGL(xg_kernel, dim3(Tseg), dim3(512), 0, stream, (const _Float16*)x,
                       w_ih_f, b_ih_f, b_hh_f, w_ih_b, b_ih_b, b_hh_b, buf0, 0, Tseg);
    for (int s = 0; s < 3; ++s) {
      _Float16* rd = (s & 1) ? buf1 : buf0;
      _Float16* wr = (s & 1) ? buf0 : buf1;
      hipLaunchKernelGGL(lstm_xg_kernel, dim3(8 + Tseg / 2), dim3(1024), 0, stream,
                         (const _Float16*)rd, wr, (const _Float16*)x, w_hh_f, w_hh_b,
                         w_ih_f, b_ih_f, b_hh_f, w_ih_b, b_ih_b, b_hh_b,
                         h_cat, h_state, c_state, s, s + 1, Tseg);
    }
    hipLaunchKernelGGL(lstm_xg_kernel, dim3(8), dim3(1024), 0, stream,
                       (const _Float16*)buf1, buf0, (const _Float16*)x, w_hh_f, w_hh_b,
                       w_ih_f, b_ih_f, b_hh_f, w_ih_b, b_ih_b, b_hh_b,
                       h_cat, h_state, c_state, 3, 0, Tseg);
    hipLaunchKernelGGL(emis_kernel, dim3(2048), dim3(256), 0, stream, h_cat, w_proj, b_proj, em,
                       expem);
    hipLaunchKernelGGL(mcrf_kernel, dim3(2176), dim3(64), 0, stream, em,
                       (const _Float16*)expem, trans, tags, start_trans, end_trans, Nbuf, lzbuf,
                       num);
    hipLaunchKernelGGL(merge_kernel, dim3(128), dim3(64), 0, stream, (const _Float16*)Nbuf,
                       lzbuf, em, start_trans, end_trans, denom);
    hipLaunchKernelGGL(final_kernel, dim3(1), dim3(128), 0, stream, denom, num, out);
  } else {
    int nseg;
    if (ws_size >= 167969792ull) nseg = 4;
    else if (ws_size >= 134415360ull) nseg = 8;
    else nseg = 16;
    const int Tseg = TT / nseg;
    const size_t xg_bytes = 268435456ull / (size_t)nseg;
    _Float16* xgbuf = (_Float16*)(ws + 100663296);
    _Float16* expem = (_Float16*)(ws + 100663296);
    _Float16* h_state = (_Float16*)(ws + 100663296 + xg_bytes);
    float* c_state = (float*)(ws + 100663296 + xg_bytes + 65536);

    hipLaunchKernelGGL(initembed_kernel, dim3(16432), dim3(256), 0, stream, kmers, emb, x,
                       (float4_t*)h_state);
    for (int s = 0; s < nseg; ++s) {
      hipLaunchKernelGGL(xg_kernel, dim3(Tseg), dim3(512), 0, stream, (const _Float16*)x,
                         w_ih_f, b_ih_f, b_hh_f, w_ih_b, b_ih_b, b_hh_b, xgbuf, s, Tseg);
      hipLaunchKernelGGL(lstm_xg_kernel, dim3(8), dim3(1024), 0, stream,
                         (const _Float16*)xgbuf, xgbuf, (const _Float16*)x, w_hh_f, w_hh_b,
                         w_ih_f, b_ih_f, b_hh_f, w_ih_b, b_ih_b, b_hh_b,
                         h_cat, h_state, c_state, s, s, Tseg);
    }
    hipLaunchKernelGGL(emis_kernel, dim3(2048), dim3(256), 0, stream, h_cat, w_proj, b_proj, em,
                       expem);
    hipLaunchKernelGGL(mcrf_kernel, dim3(2176), dim3(64), 0, stream, em,
                       (const _Float16*)expem, trans, tags, start_trans, end_trans, Nbuf, lzbuf,
                       num);
    hipLaunchKernelGGL(merge_kernel, dim3(128), dim3(64), 0, stream, (const _Float16*)Nbuf,
                       lzbuf, em, start_trans, end_trans, denom);
    hipLaunchKernelGGL(final_kernel, dim3(1), dim3(128), 0, stream, denom, num, out);
  }
}

// Round 10
// 1019.041 us; speedup vs baseline: 3.1055x; 3.1022x over previous
//
#include <hip/hip_runtime.h>
#include <hip/hip_bf16.h>

typedef _Float16 half8_t __attribute__((ext_vector_type(8)));
typedef _Float16 half4_t __attribute__((ext_vector_type(4)));
typedef _Float16 half2_t __attribute__((ext_vector_type(2)));
typedef float float4_t __attribute__((ext_vector_type(4)));
typedef unsigned int uint2_t __attribute__((ext_vector_type(2)));

#define TT 1024
#define BB 128
#define EE 128
#define HH 128
#define NTAG 64
#define ASTR 144  // [batch][hu] LDS panel stride (f16) — R6-proven for the b128 read pattern

__device__ __forceinline__ float fast_exp(float x) {
  return __builtin_amdgcn_exp2f(x * 1.44269504088896f);
}
// LDS-only barrier: does NOT drain vmcnt -> global loads/stores stay in flight.
__device__ __forceinline__ void lds_barrier() {
  asm volatile("s_waitcnt lgkmcnt(0)\n\ts_barrier" ::: "memory");
}
// Single-wave LDS write->read fence.
__device__ __forceinline__ void lds_fence() {
  asm volatile("s_waitcnt lgkmcnt(0)" ::: "memory");
}
__device__ __forceinline__ half2_t cvt_pk(float a, float b) {
  return __builtin_bit_cast(half2_t, __builtin_amdgcn_cvt_pkrtz(a, b));
}
__device__ __forceinline__ half2_t h2bc(float v) {
  _Float16 h = (_Float16)v;
  half2_t r; r[0] = h; r[1] = h;
  return r;
}
__device__ __forceinline__ half8_t h8bc(float v) {
  _Float16 h = (_Float16)v;
  half8_t r;
#pragma unroll
  for (int i = 0; i < 8; ++i) r[i] = h;
  return r;
}
// max over the 4 quads (lane bits 4,5) for each n16 column — pure VALU (permlane swaps)
__device__ __forceinline__ float quad_max4(float v) {
  unsigned a = __builtin_bit_cast(unsigned, v);
  uint2_t r = __builtin_amdgcn_permlane32_swap(a, a, false, false);
  float m = fmaxf(__builtin_bit_cast(float, r[0]), __builtin_bit_cast(float, r[1]));
  unsigned b = __builtin_bit_cast(unsigned, m);
  uint2_t s = __builtin_amdgcn_permlane16_swap(b, b, false, false);
  return fmaxf(__builtin_bit_cast(float, s[0]), __builtin_bit_cast(float, s[1]));
}
// deg-5 odd tanh poly (fit at 1, 1.6; clamp +-1.6): 6 pk instrs
__device__ __forceinline__ half2_t tanh6(half2_t x) {
  half2_t y = __builtin_elementwise_min(__builtin_elementwise_max(x, h2bc(-1.6f)), h2bc(1.6f));
  half2_t u = y * y;
  half2_t p = u * h2bc(0.04667f) + h2bc(-0.28507f);
  p = u * p + h2bc(1.0f);
  return y * p;
}
// sigmoid, x/2 folded into coefficients: 6 pk instrs
__device__ __forceinline__ half2_t sig6(half2_t x) {
  half2_t y = __builtin_elementwise_min(__builtin_elementwise_max(x, h2bc(-3.2f)), h2bc(3.2f));
  half2_t u = y * y;
  half2_t q = u * h2bc(0.00072921875f) + h2bc(-0.017816875f);
  q = u * q + h2bc(0.25f);
  return y * q + h2bc(0.5f);
}

// ---------------------------------------------------------------- init + embed (fused, independent)
__global__ __launch_bounds__(256) void initembed_kernel(const int* __restrict__ kmers,
                                                        const float* __restrict__ emb,
                                                        half4_t* __restrict__ x,
                                                        float4_t* __restrict__ state) {
  if (blockIdx.x < 48) {
    state[blockIdx.x * 256 + threadIdx.x] = (float4_t){0.f, 0.f, 0.f, 0.f};
    return;
  }
  const int g = (blockIdx.x - 48) * 256 + threadIdx.x;
  const int row = g >> 5, seg = g & 31;
  const int km = kmers[row];
  const float4_t v = ((const float4_t*)(emb + (size_t)km * EE))[seg];
  half4_t o;
  o[0] = (_Float16)v[0]; o[1] = (_Float16)v[1];
  o[2] = (_Float16)v[2]; o[3] = (_Float16)v[3];
  x[(size_t)row * 32 + seg] = o;
}

// ---------------------------------------------------------------- xg body (device)
// Orientation: A = W_ih (regs), B = x^T (b128 global loads), C rows=hu-part, col=batch.
__device__ __forceinline__ void xg_body(
    int wg, int tid, const _Float16* __restrict__ x,
    const float* __restrict__ w_ih_f, const float* __restrict__ b_ih_f, const float* __restrict__ b_hh_f,
    const float* __restrict__ w_ih_b, const float* __restrict__ b_ih_b, const float* __restrict__ b_hh_b,
    _Float16* __restrict__ xgbuf, int s, int Tseg) {
  const int nt = Tseg >> 4;
  const int dir = wg / (8 * nt);
  const int rem = wg - dir * 8 * nt;
  const int chunk = rem / nt;
  const int tb = rem - chunk * nt;
  const int wave = tid >> 6, lane = tid & 63;
  const int n16 = lane & 15, quad = lane >> 4;

  const float* wih = dir ? w_ih_b : w_ih_f;
  const float* bih = dir ? b_ih_b : b_ih_f;
  const float* bhh = dir ? b_hh_b : b_hh_f;

  half8_t wf[4][4];
#pragma unroll
  for (int g = 0; g < 4; ++g) {
    const int row = g * HH + wave * 16 + n16;
#pragma unroll
    for (int kf = 0; kf < 4; ++kf) {
      const float* src = wih + row * EE + kf * 32 + quad * 8;
#pragma unroll
      for (int i = 0; i < 8; ++i) wf[g][kf][i] = (_Float16)src[i];
    }
  }
  float4_t bias4[4];
#pragma unroll
  for (int g = 0; g < 4; ++g) {
    const int row = g * HH + wave * 16 + quad * 4;
    const float4_t bi = *(const float4_t*)(bih + row);
    const float4_t bh = *(const float4_t*)(bhh + row);
    bias4[g] = bi + bh;
  }

  const int l0 = tb * 16;
  half8_t xb[4];
  {
    const int te = dir ? (TT - 1 - (s * Tseg + l0)) : (s * Tseg + l0);
#pragma unroll
    for (int kf = 0; kf < 4; ++kf)
      xb[kf] = *(const half8_t*)(x + ((size_t)te * BB + chunk * 16 + n16) * EE + kf * 32 + quad * 8);
  }
  for (int u = 0; u < 16; ++u) {
    const int l = l0 + u;
    half8_t xn[4] = {};
    if (u < 15) {
      const int tn = dir ? (TT - 1 - (s * Tseg + l + 1)) : (s * Tseg + l + 1);
#pragma unroll
      for (int kf = 0; kf < 4; ++kf)
        xn[kf] = *(const half8_t*)(x + ((size_t)tn * BB + chunk * 16 + n16) * EE + kf * 32 + quad * 8);
    }
    float4_t acc[4];
#pragma unroll
    for (int g = 0; g < 4; ++g) acc[g] = bias4[g];
#pragma unroll
    for (int kf = 0; kf < 4; ++kf)
#pragma unroll
      for (int g = 0; g < 4; ++g)
        acc[g] = __builtin_amdgcn_mfma_f32_16x16x32_f16(wf[g][kf], xb[kf], acc[g], 0, 0, 0);
    half8_t ho0, ho1;
#pragma unroll
    for (int r = 0; r < 4; ++r) {
      ho0[r] = (_Float16)acc[0][r];
      ho0[4 + r] = (_Float16)acc[1][r];
      ho1[r] = (_Float16)acc[2][r];
      ho1[4 + r] = (_Float16)acc[3][r];
    }
    _Float16* ob = xgbuf + (size_t)dir * Tseg * 65536 + (size_t)l * 65536 + chunk * 8192 +
                   wave * 1024 + lane * 16;
    *(half8_t*)ob = ho0;
    *(half8_t*)(ob + 8) = ho1;
#pragma unroll
    for (int kf = 0; kf < 4; ++kf) xb[kf] = xn[kf];
  }
}

// ---------------------------------------------------------------- standalone xg (first segment)
__global__ __launch_bounds__(512) void xg_kernel(
    const _Float16* __restrict__ x,
    const float* __restrict__ w_ih_f, const float* __restrict__ b_ih_f, const float* __restrict__ b_hh_f,
    const float* __restrict__ w_ih_b, const float* __restrict__ b_ih_b, const float* __restrict__ b_hh_b,
    _Float16* __restrict__ xgbuf, int s, int Tseg) {
  xg_body(blockIdx.x, threadIdx.x, x, w_ih_f, b_ih_f, b_hh_f, w_ih_b, b_ih_b, b_hh_b, xgbuf, s,
          Tseg);
}

// ---------------------------------------------------------------- fused: lstm(s) + xg(s+1)
// REVERTED to the R4/R6-proven 512-thread structure (162.7 us/dispatch, VGPR 76):
// blocks 0..15 = one (dir,chunk) LSTM chain each (8 waves); blocks 16+ = one xg unit each.
// R7-R9 lesson: 1024-thread 16-wave blocks are pinned to a 64-VGPR cap by this toolchain
// (all of default/(1024,4)/(1024,1) emitted VGPR=64 -> wf[] spills -> +110MB scratch, 716us).
// NEW vs R4: 2-deep split MFMA accumulation (accA: kf0-1, accB: kf2-3, then add) — shortens
// the per-step MFMA dependency chain from 4 to 2 + one f32 add (off critical path).
__global__ __launch_bounds__(512, 2) void lstm_xg_kernel(
    const _Float16* __restrict__ xgrd, _Float16* __restrict__ xgwr,
    const _Float16* __restrict__ x,
    const float* __restrict__ w_hh_f, const float* __restrict__ w_hh_b,
    const float* __restrict__ w_ih_f, const float* __restrict__ b_ih_f, const float* __restrict__ b_hh_f,
    const float* __restrict__ w_ih_b, const float* __restrict__ b_ih_b, const float* __restrict__ b_hh_b,
    _Float16* __restrict__ h_cat, _Float16* __restrict__ h_state, float* __restrict__ c_state,
    int s, int sx, int Tseg) {
  __shared__ _Float16 A[2][16 * ASTR];
  if (blockIdx.x >= 16) {
    xg_body(blockIdx.x - 16, threadIdx.x, x, w_ih_f, b_ih_f, b_hh_f, w_ih_b, b_ih_b, b_hh_b,
            xgwr, sx, Tseg);
    return;
  }
  const int wg = blockIdx.x;
  const int dir = wg >> 3, chunk = wg & 7;
  const int b0 = chunk * 16;
  const float* w_hh = dir ? w_hh_b : w_hh_f;
  const int tid = threadIdx.x;
  const int wave = tid >> 6, lane = tid & 63;
  const int n16 = lane & 15, quad = lane >> 4;

  half8_t wf[4][4];
#pragma unroll
  for (int g = 0; g < 4; ++g) {
    const int row = g * HH + wave * 16 + n16;
#pragma unroll
    for (int kf = 0; kf < 4; ++kf) {
      const float* src = w_hh + row * HH + kf * 32 + quad * 8;
#pragma unroll
      for (int i = 0; i < 8; ++i) wf[g][kf][i] = (_Float16)src[i];
    }
  }
  // persistent state: layout identical to R5 ((dir*8+chunk)*8+wave)
  const int sidx = ((wg * 8 + wave) * 64 + lane) * 4;
  half4_t h4 = *(const half4_t*)(h_state + sidx);
  float4_t c4 = *(const float4_t*)(c_state + sidx);
  half2_t c2[2];
  c2[0] = cvt_pk(c4[0], c4[1]);
  c2[1] = cvt_pk(c4[2], c4[3]);
  *(half4_t*)(&A[0][n16 * ASTR + wave * 16 + quad * 4]) = h4;  // seed h_{-1}

  const _Float16* xgw =
      xgrd + (size_t)dir * Tseg * 65536 + chunk * 8192 + wave * 1024 + (size_t)lane * 16;
  half4_t hlast = h4;
  const float4_t z4 = {0.f, 0.f, 0.f, 0.f};
  const int te0 = dir ? (TT - 1 - s * Tseg) : (s * Tseg);
  _Float16* gp_run =
      h_cat + ((size_t)te0 * BB + b0 + n16) * 256 + dir * HH + wave * 16 + quad * 4;
  const ptrdiff_t dstep = dir ? -(ptrdiff_t)32768 : (ptrdiff_t)32768;

  // 4-deep in-place xg prefetch ring (static indices)
  half8_t pf0[4], pf1[4];
#pragma unroll
  for (int j = 0; j < 4; ++j) {
    const _Float16* p = xgw + (size_t)j * 65536;
    pf0[j] = *(const half8_t*)p;
    pf1[j] = *(const half8_t*)(p + 8);
  }

#define LSTM_STEP(AB, AN, X0, X1)                                                          \
  {                                                                                        \
    const _Float16* Abp = &AB[0];                                                          \
    _Float16* Anp = &AN[0];                                                                \
    half8_t hb0 = *(const half8_t*)(Abp + n16 * ASTR + 0 * 32 + quad * 8);                 \
    half8_t hb1 = *(const half8_t*)(Abp + n16 * ASTR + 1 * 32 + quad * 8);                 \
    half8_t hb2 = *(const half8_t*)(Abp + n16 * ASTR + 2 * 32 + quad * 8);                 \
    half8_t hb3 = *(const half8_t*)(Abp + n16 * ASTR + 3 * 32 + quad * 8);                 \
    float4_t accA[4], accB[4];                                                             \
    _Pragma("unroll") for (int g = 0; g < 4; ++g) {                                        \
      accA[g] = __builtin_amdgcn_mfma_f32_16x16x32_f16(wf[g][0], hb0, z4, 0, 0, 0);        \
    }                                                                                      \
    _Pragma("unroll") for (int g = 0; g < 4; ++g) {                                        \
      accB[g] = __builtin_amdgcn_mfma_f32_16x16x32_f16(wf[g][2], hb2, z4, 0, 0, 0);        \
    }                                                                                      \
    _Pragma("unroll") for (int g = 0; g < 4; ++g) {                                        \
      accA[g] = __builtin_amdgcn_mfma_f32_16x16x32_f16(wf[g][1], hb1, accA[g], 0, 0, 0);   \
    }                                                                                      \
    _Pragma("unroll") for (int g = 0; g < 4; ++g) {                                        \
      accB[g] = __builtin_amdgcn_mfma_f32_16x16x32_f16(wf[g][3], hb3, accB[g], 0, 0, 0);   \
    }                                                                                      \
    _Pragma("unroll") for (int g = 0; g < 4; ++g) { accA[g] = accA[g] + accB[g]; }         \
    const half2_t* x0p = (const half2_t*)&X0;                                              \
    const half2_t* x1p = (const half2_t*)&X1;                                              \
    half4_t hstore;                                                                        \
    _Pragma("unroll") for (int p = 0; p < 2; ++p) {                                        \
      const half2_t i_ = sig6(cvt_pk(accA[0][2 * p], accA[0][2 * p + 1]) + x0p[p]);        \
      const half2_t f_ = sig6(cvt_pk(accA[1][2 * p], accA[1][2 * p + 1]) + x0p[2 + p]);    \
      const half2_t g_ = tanh6(cvt_pk(accA[2][2 * p], accA[2][2 * p + 1]) + x1p[p]);       \
      const half2_t o_ = sig6(cvt_pk(accA[3][2 * p], accA[3][2 * p + 1]) + x1p[2 + p]);    \
      c2[p] = f_ * c2[p] + i_ * g_;                                                        \
      const half2_t hh = o_ * tanh6(c2[p]);                                                \
      hstore[2 * p] = hh[0];                                                               \
      hstore[2 * p + 1] = hh[1];                                                           \
    }                                                                                      \
    *(half4_t*)(Anp + n16 * ASTR + wave * 16 + quad * 4) = hstore;                         \
    *(half4_t*)gp_run = hstore;                                                            \
    hlast = hstore;                                                                        \
  }

  // main loop: prefetch il+j+4 <= Tseg-1, no clamp needed
  for (int il = 0; il < Tseg - 4; il += 4) {
#pragma unroll
    for (int j = 0; j < 4; ++j) {
      lds_barrier();
      if (j & 1) {
        LSTM_STEP(A[1], A[0], pf0[j], pf1[j]);
      } else {
        LSTM_STEP(A[0], A[1], pf0[j], pf1[j]);
      }
      const _Float16* p = xgw + (size_t)(il + j + 4) * 65536;
      pf0[j] = *(const half8_t*)p;
      pf1[j] = *(const half8_t*)(p + 8);
      gp_run += dstep;
    }
  }
  // tail: last 4 steps, no prefetch
#pragma unroll
  for (int j = 0; j < 4; ++j) {
    lds_barrier();
    if (j & 1) {
      LSTM_STEP(A[1], A[0], pf0[j], pf1[j]);
    } else {
      LSTM_STEP(A[0], A[1], pf0[j], pf1[j]);
    }
    gp_run += dstep;
  }
#undef LSTM_STEP

  *(half4_t*)(h_state + sidx) = hlast;
  c4[0] = (float)c2[0][0]; c4[1] = (float)c2[0][1];
  c4[2] = (float)c2[1][0]; c4[3] = (float)c2[1][1];
  *(float4_t*)(c_state + sidx) = c4;
}

// ---------------------------------------------------------------- emissions: em f32 + expem f16
__global__ __launch_bounds__(256) void emis_kernel(const _Float16* __restrict__ h_cat,
                                                   const float* __restrict__ w_proj,
                                                   const float* __restrict__ b_proj,
                                                   float* __restrict__ em,
                                                   _Float16* __restrict__ expem) {
  const int tid = threadIdx.x;
  const int wave = tid >> 6, lane = tid & 63;
  const int n16 = lane & 15, quad = lane >> 4;
  const size_t row0 = (size_t)blockIdx.x * 64 + wave * 16;

  half8_t bf[4][8];
#pragma unroll
  for (int nt = 0; nt < 4; ++nt) {
    const float* wp = w_proj + (nt * 16 + n16) * 256;
#pragma unroll
    for (int kf = 0; kf < 8; ++kf) {
      const int kb = kf * 32 + quad * 8;
#pragma unroll
      for (int i = 0; i < 8; ++i) bf[nt][kf][i] = (_Float16)wp[kb + i];
    }
  }
  float4_t acc[4];
#pragma unroll
  for (int nt = 0; nt < 4; ++nt) {
    const float bv = b_proj[nt * 16 + n16];
    acc[nt] = (float4_t){bv, bv, bv, bv};
  }
#pragma unroll
  for (int kf = 0; kf < 8; ++kf) {
    half8_t af = *(const half8_t*)(h_cat + (row0 + n16) * 256 + kf * 32 + quad * 8);
#pragma unroll
    for (int nt = 0; nt < 4; ++nt)
      acc[nt] = __builtin_amdgcn_mfma_f32_16x16x32_f16(af, bf[nt][kf], acc[nt], 0, 0, 0);
  }
#pragma unroll
  for (int nt = 0; nt < 4; ++nt)
#pragma unroll
    for (int r = 0; r < 4; ++r) {
      const size_t idx = (row0 + quad * 4 + r) * NTAG + nt * 16 + n16;
      em[idx] = acc[nt][r];
      expem[idx] = (_Float16)fast_exp(acc[nt][r]);
    }
}

// ---------------------------------------------------------------- segment-parallel CRF matrices
// 2048 chains (128 batches x 16 segments), 1 wave each: N <- diag(g_t) (E^T N), N init = I.
// Stored as Nbuf[b][s][c][k] = N[k][c] = P_s[c][k]. Blocks >= 2048: CRF numerator.
__global__ __launch_bounds__(64) void mcrf_kernel(const float* __restrict__ em,
                                                  const _Float16* __restrict__ expem,
                                                  const float* __restrict__ trans,
                                                  const int* __restrict__ tags,
                                                  const float* __restrict__ start_trans,
                                                  const float* __restrict__ end_trans,
                                                  _Float16* __restrict__ Nbuf,
                                                  float* __restrict__ lzbuf,
                                                  float* __restrict__ num) {
  const int lane = threadIdx.x;
  if (blockIdx.x >= 2048) {  // ---------------- numerator (1 wave per batch)
    const int nb = blockIdx.x - 2048;
    const int tg = tags[nb];
    float acc = 0.f;
    for (int t = lane; t < TT; t += 64)
      acc += em[((size_t)t * BB + nb) * NTAG + tg];
#pragma unroll
    for (int off = 32; off > 0; off >>= 1) acc += __shfl_xor(acc, off, 64);
    if (lane == 0)
      num[nb] = start_trans[tg] + end_trans[tg] + 1023.0f * trans[tg * NTAG + tg] + acc;
    return;
  }
  const int n16 = lane & 15, quad = lane >> 4;
  const int b = blockIdx.x >> 4;
  const int s = blockIdx.x & 15;

  half8_t efA[4][2];
#pragma unroll
  for (int mt = 0; mt < 4; ++mt)
#pragma unroll
    for (int kf = 0; kf < 2; ++kf)
#pragma unroll
      for (int i = 0; i < 8; ++i) {
        const int m = mt * 16 + n16, k = kf * 32 + quad * 8 + i;
        efA[mt][kf][i] = (_Float16)(fast_exp(trans[k * NTAG + m]) * 0.015625f);
      }

  half8_t pb[4][2];
#pragma unroll
  for (int tile = 0; tile < 4; ++tile)
#pragma unroll
    for (int kf = 0; kf < 2; ++kf)
#pragma unroll
      for (int i = 0; i < 8; ++i) {
        const int k = kf * 32 + quad * 8 + i;
        pb[tile][kf][i] = (_Float16)((k == tile * 16 + n16) ? 1.f : 0.f);
      }

  float lz2 = 0.f;
  const float4_t z4 = {0.f, 0.f, 0.f, 0.f};
  const _Float16* exb = expem + (size_t)b * NTAG;
  const int t0 = s * 64 + 1;
  const int nsteps = (s == 15) ? 63 : 64;

#define MCRF_CORE(PB0, PB1, NB0, NB1)                                                      \
  {                                                                                        \
    float4_t a0 = __builtin_amdgcn_mfma_f32_16x16x32_f16(efA[0][0], PB0, z4, 0, 0, 0);     \
    float4_t a1 = __builtin_amdgcn_mfma_f32_16x16x32_f16(efA[1][0], PB0, z4, 0, 0, 0);     \
    float4_t a2 = __builtin_amdgcn_mfma_f32_16x16x32_f16(efA[2][0], PB0, z4, 0, 0, 0);     \
    float4_t a3 = __builtin_amdgcn_mfma_f32_16x16x32_f16(efA[3][0], PB0, z4, 0, 0, 0);     \
    a0 = __builtin_amdgcn_mfma_f32_16x16x32_f16(efA[0][1], PB1, a0, 0, 0, 0);              \
    a1 = __builtin_amdgcn_mfma_f32_16x16x32_f16(efA[1][1], PB1, a1, 0, 0, 0);              \
    a2 = __builtin_amdgcn_mfma_f32_16x16x32_f16(efA[2][1], PB1, a2, 0, 0, 0);              \
    a3 = __builtin_amdgcn_mfma_f32_16x16x32_f16(efA[3][1], PB1, a3, 0, 0, 0);              \
    half2_t dpk[4][2];                                                                     \
    dpk[0][0] = cvt_pk(a0[0], a0[1]); dpk[0][1] = cvt_pk(a0[2], a0[3]);                    \
    dpk[1][0] = cvt_pk(a1[0], a1[1]); dpk[1][1] = cvt_pk(a1[2], a1[3]);                    \
    dpk[2][0] = cvt_pk(a2[0], a2[1]); dpk[2][1] = cvt_pk(a2[2], a2[3]);                    \
    dpk[3][0] = cvt_pk(a3[0], a3[1]); dpk[3][1] = cvt_pk(a3[2], a3[3]);                    \
    half2_t* wwp0 = (half2_t*)&NB0;                                                        \
    half2_t* wwp1 = (half2_t*)&NB1;                                                        \
    _Pragma("unroll") for (int kf = 0; kf < 2; ++kf) {                                     \
      half2_t* wp = kf ? wwp1 : wwp0;                                                      \
      _Pragma("unroll") for (int p = 0; p < 2; ++p) {                                      \
        const unsigned Xu = __builtin_bit_cast(unsigned, dpk[2 * kf][p]);                  \
        const unsigned Yu = __builtin_bit_cast(unsigned, dpk[2 * kf + 1][p]);              \
        uint2_t r1 = __builtin_amdgcn_permlane32_swap(Xu, Yu, false, false);               \
        uint2_t r2 = __builtin_amdgcn_permlane16_swap(r1[0], r1[1], false, false);         \
        wp[p] = __builtin_bit_cast(half2_t, r2[0]);                                        \
        wp[2 + p] = __builtin_bit_cast(half2_t, r2[1]);                                    \
      }                                                                                    \
    }                                                                                      \
  }

#define MSTEP(GC0, GC1, IT)                                                                \
  {                                                                                        \
    _Pragma("unroll") for (int tile = 0; tile < 4; ++tile) {                               \
      half8_t nb0, nb1;                                                                    \
      MCRF_CORE(pb[tile][0], pb[tile][1], nb0, nb1)                                        \
      pb[tile][0] = nb0 * GC0;                                                             \
      pb[tile][1] = nb1 * GC1;                                                             \
    }                                                                                      \
    if (((IT) & 15) == 15) {                                                               \
      half8_t m8 = __builtin_elementwise_max(pb[0][0], pb[0][1]);                          \
      m8 = __builtin_elementwise_max(m8, __builtin_elementwise_max(pb[1][0], pb[1][1]));   \
      m8 = __builtin_elementwise_max(m8, __builtin_elementwise_max(pb[2][0], pb[2][1]));   \
      m8 = __builtin_elementwise_max(m8, __builtin_elementwise_max(pb[3][0], pb[3][1]));   \
      float mm = (float)m8[0];                                                             \
      _Pragma("unroll") for (int i = 1; i < 8; ++i) mm = fmaxf(mm, (float)m8[i]);          \
      mm = quad_max4(mm);                                                                  \
      mm = fmaxf(mm, __shfl_xor(mm, 1, 64));                                               \
      mm = fmaxf(mm, __shfl_xor(mm, 2, 64));                                               \
      mm = fmaxf(mm, __shfl_xor(mm, 4, 64));                                               \
      mm = fmaxf(mm, __shfl_xor(mm, 8, 64));                                               \
      lz2 += __builtin_amdgcn_logf(mm);                                                    \
      const half8_t rc8 = h8bc(__builtin_amdgcn_rcpf(mm));                                 \
      _Pragma("unroll") for (int tile = 0; tile < 4; ++tile) {                             \
        pb[tile][0] *= rc8;                                                                \
        pb[tile][1] *= rc8;                                                                \
      }                                                                                    \
    }                                                                                      \
  }

  half8_t pre0[4], pre1[4];
#pragma unroll
  for (int j = 0; j < 4; ++j) {
    const size_t tt = (size_t)(t0 + j) * 8192;
    pre0[j] = *(const half8_t*)(exb + tt + quad * 8);
    pre1[j] = *(const half8_t*)(exb + tt + 32 + quad * 8);
  }
  int it = 0;
  const int full4 = nsteps >> 2;
  for (int grp = 0; grp < full4; ++grp) {
#pragma unroll
    for (int j = 0; j < 4; ++j) {
      const half8_t gc0 = pre0[j], gc1 = pre1[j];
      int tf = t0 + it + 4;
      tf = tf > 1023 ? 1023 : tf;
      const size_t tt = (size_t)tf * 8192;
      pre0[j] = *(const half8_t*)(exb + tt + quad * 8);
      pre1[j] = *(const half8_t*)(exb + tt + 32 + quad * 8);
      MSTEP(gc0, gc1, it)
      ++it;
    }
  }
  for (; it < nsteps; ++it) {
    const size_t tt = (size_t)(t0 + it) * 8192;
    const half8_t gc0 = *(const half8_t*)(exb + tt + quad * 8);
    const half8_t gc1 = *(const half8_t*)(exb + tt + 32 + quad * 8);
    MSTEP(gc0, gc1, it)
  }
#undef MSTEP
#undef MCRF_CORE

  _Float16* nb = Nbuf + ((size_t)b * 16 + s) * 4096;
#pragma unroll
  for (int tile = 0; tile < 4; ++tile) {
    const int col = tile * 16 + n16;
#pragma unroll
    for (int kf = 0; kf < 2; ++kf)
      *(half8_t*)(nb + (size_t)col * 64 + kf * 32 + quad * 8) = pb[tile][kf];
  }
  if (lane == 0) lzbuf[b * 16 + s] = lz2;
}

// ---------------------------------------------------------------- merge: w <- P_s w, then alpha0 dot
__global__ __launch_bounds__(64) void merge_kernel(const _Float16* __restrict__ Nbuf,
                                                   const float* __restrict__ lzbuf,
                                                   const float* __restrict__ em,
                                                   const float* __restrict__ start_trans,
                                                   const float* __restrict__ end_trans,
                                                   float* __restrict__ denom) {
  const int b = blockIdx.x, m = threadIdx.x;
  __shared__ float w[64];
  float L2 = 0.f;
  w[m] = fast_exp(end_trans[m]);
  for (int s = 15; s >= 0; --s) {
    lds_fence();
    const _Float16* row = Nbuf + (((size_t)b * 16 + s) * 64 + m) * 64;
    float acc = 0.f;
#pragma unroll
    for (int kf = 0; kf < 8; ++kf) {
      const half8_t rv = *(const half8_t*)(row + kf * 8);
#pragma unroll
      for (int i = 0; i < 8; ++i) acc += (float)rv[i] * w[kf * 8 + i];
    }
    float mx = acc;
#pragma unroll
    for (int off = 32; off > 0; off >>= 1) mx = fmaxf(mx, __shfl_xor(mx, off, 64));
    L2 += __builtin_amdgcn_logf(mx) + lzbuf[b * 16 + s];
    const float inv = __builtin_amdgcn_rcpf(mx);
    lds_fence();
    w[m] = acc * inv;
  }
  lds_fence();
  const float sv = start_trans[m] + em[(size_t)b * NTAG + m];  // t=0 row
  float m0 = sv;
#pragma unroll
  for (int off = 32; off > 0; off >>= 1) m0 = fmaxf(m0, __shfl_xor(m0, off, 64));
  float z = fast_exp(sv - m0) * w[m];
#pragma unroll
  for (int off = 32; off > 0; off >>= 1) z += __shfl_xor(z, off, 64);
  if (m == 0)
    denom[b] = m0 + 0.693147180559945f * (L2 + 6138.0f + __builtin_amdgcn_logf(z));
}

// ---------------------------------------------------------------- final: reduce (denom - num)
__global__ __launch_bounds__(128) void final_kernel(const float* __restrict__ denom,
                                                    const float* __restrict__ num,
                                                    float* __restrict__ out) {
  const int tid = threadIdx.x;
  float v = denom[tid] - num[tid];
#pragma unroll
  for (int off = 32; off > 0; off >>= 1) v += __shfl_xor(v, off, 64);
  __shared__ float red[2];
  if ((tid & 63) == 0) red[tid >> 6] = v;
  __syncthreads();
  if (tid == 0) out[0] = red[0] + red[1];
}

extern "C" void kernel_launch(void* const* d_in, const int* in_sizes, int n_in,
                              void* d_out, int out_size, void* d_ws, size_t ws_size,
                              hipStream_t stream) {
  const int* kmers = (const int*)d_in[0];
  const int* tags = (const int*)d_in[1];
  const float* emb = (const float*)d_in[2];
  const float* w_ih_f = (const float*)d_in[3];
  const float* w_hh_f = (const float*)d_in[4];
  const float* b_ih_f = (const float*)d_in[5];
  const float* b_hh_f = (const float*)d_in[6];
  const float* w_ih_b = (const float*)d_in[7];
  const float* w_hh_b = (const float*)d_in[8];
  const float* b_ih_b = (const float*)d_in[9];
  const float* b_hh_b = (const float*)d_in[10];
  const float* w_proj = (const float*)d_in[11];
  const float* b_proj = (const float*)d_in[12];
  const float* start_trans = (const float*)d_in[13];
  const float* end_trans = (const float*)d_in[14];
  const float* trans = (const float*)d_in[15];

  char* ws = (char*)d_ws;
  half4_t* x = (half4_t*)ws;                       // [0, 33.5M); em aliases after xg done
  _Float16* h_cat = (_Float16*)(ws + 33554432);    // [33.5M, 100.7M)
  float* em = (float*)ws;
  float* out = (float*)d_out;
  // post-emis overlays of the dead h_cat region (path-independent):
  _Float16* Nbuf = (_Float16*)(ws + 33554432);            // 16.8 MB
  float* lzbuf = (float*)(ws + 33554432 + 16777216);      // 8 KB
  float* denom = (float*)(ws + 33554432 + 16785408);      // 512 B
  float* num = (float*)(ws + 33554432 + 16785920);        // 512 B

  const bool fused = ws_size >= 235078656ull;
  if (fused) {
    const int Tseg = 256;
    _Float16* buf0 = (_Float16*)(ws + 100663296);              // 64 MB
    _Float16* buf1 = (_Float16*)(ws + 100663296 + 67108864);   // 64 MB
    _Float16* expem = (_Float16*)(ws + 100663296);             // aliases buf0 (dead after lstm)
    _Float16* h_state = (_Float16*)(ws + 100663296 + 134217728);
    float* c_state = (float*)(ws + 100663296 + 134217728 + 65536);

    hipLaunchKernelGGL(initembed_kernel, dim3(16432), dim3(256), 0, stream, kmers, emb, x,
                       (float4_t*)h_state);
    hipLaunchKernelGGL(xg_kernel, dim3(Tseg), dim3(512), 0, stream, (const _Float16*)x,
                       w_ih_f, b_ih_f, b_hh_f, w_ih_b, b_ih_b, b_hh_b, buf0, 0, Tseg);
    for (int s = 0; s < 3; ++s) {
      _Float16* rd = (s & 1) ? buf1 : buf0;
      _Float16* wr = (s & 1) ? buf0 : buf1;
      hipLaunchKernelGGL(lstm_xg_kernel, dim3(16 + Tseg), dim3(512), 0, stream,
                         (const _Float16*)rd, wr, (const _Float16*)x, w_hh_f, w_hh_b,
                         w_ih_f, b_ih_f, b_hh_f, w_ih_b, b_ih_b, b_hh_b,
                         h_cat, h_state, c_state, s, s + 1, Tseg);
    }
    hipLaunchKernelGGL(lstm_xg_kernel, dim3(16), dim3(512), 0, stream,
                       (const _Float16*)buf1, buf0, (const _Float16*)x, w_hh_f, w_hh_b,
                       w_ih_f, b_ih_f, b_hh_f, w_ih_b, b_ih_b, b_hh_b,
                       h_cat, h_state, c_state, 3, 0, Tseg);
    hipLaunchKernelGGL(emis_kernel, dim3(2048), dim3(256), 0, stream, h_cat, w_proj, b_proj, em,
                       expem);
    hipLaunchKernelGGL(mcrf_kernel, dim3(2176), dim3(64), 0, stream, em,
                       (const _Float16*)expem, trans, tags, start_trans, end_trans, Nbuf, lzbuf,
                       num);
    hipLaunchKernelGGL(merge_kernel, dim3(128), dim3(64), 0, stream, (const _Float16*)Nbuf,
                       lzbuf, em, start_trans, end_trans, denom);
    hipLaunchKernelGGL(final_kernel, dim3(1), dim3(128), 0, stream, denom, num, out);
  } else {
    int nseg;
    if (ws_size >= 167969792ull) nseg = 4;
    else if (ws_size >= 134415360ull) nseg = 8;
    else nseg = 16;
    const int Tseg = TT / nseg;
    const size_t xg_bytes = 268435456ull / (size_t)nseg;
    _Float16* xgbuf = (_Float16*)(ws + 100663296);
    _Float16* expem = (_Float16*)(ws + 100663296);
    _Float16* h_state = (_Float16*)(ws + 100663296 + xg_bytes);
    float* c_state = (float*)(ws + 100663296 + xg_bytes + 65536);

    hipLaunchKernelGGL(initembed_kernel, dim3(16432), dim3(256), 0, stream, kmers, emb, x,
                       (float4_t*)h_state);
    for (int s = 0; s < nseg; ++s) {
      hipLaunchKernelGGL(xg_kernel, dim3(Tseg), dim3(512), 0, stream, (const _Float16*)x,
                         w_ih_f, b_ih_f, b_hh_f, w_ih_b, b_ih_b, b_hh_b, xgbuf, s, Tseg);
      hipLaunchKernelGGL(lstm_xg_kernel, dim3(16), dim3(512), 0, stream,
                         (const _Float16*)xgbuf, xgbuf, (const _Float16*)x, w_hh_f, w_hh_b,
                         w_ih_f, b_ih_f, b_hh_f, w_ih_b, b_ih_b, b_hh_b,
                         h_cat, h_state, c_state, s, s, Tseg);
    }
    hipLaunchKernelGGL(emis_kernel, dim3(2048), dim3(256), 0, stream, h_cat, w_proj, b_proj, em,
                       expem);
    hipLaunchKernelGGL(mcrf_kernel, dim3(2176), dim3(64), 0, stream, em,
                       (const _Float16*)expem, trans, tags, start_trans, end_trans, Nbuf, lzbuf,
                       num);
    hipLaunchKernelGGL(merge_kernel, dim3(128), dim3(64), 0, stream, (const _Float16*)Nbuf,
                       lzbuf, em, start_trans, end_trans, denom);
    hipLaunchKernelGGL(final_kernel, dim3(1), dim3(128), 0, stream, denom, num, out);
  }
}

// Round 11
// 957.821 us; speedup vs baseline: 3.3040x; 1.0639x over previous
//
#include <hip/hip_runtime.h>
#include <hip/hip_bf16.h>

typedef _Float16 half8_t __attribute__((ext_vector_type(8)));
typedef _Float16 half4_t __attribute__((ext_vector_type(4)));
typedef _Float16 half2_t __attribute__((ext_vector_type(2)));
typedef float float4_t __attribute__((ext_vector_type(4)));
typedef unsigned int uint2_t __attribute__((ext_vector_type(2)));

#define TT 1024
#define BB 128
#define EE 128
#define HH 128
#define NTAG 64
#define ASTR 144  // [batch][hu] LDS panel stride (f16) — R6-proven for the b128 read pattern

__device__ __forceinline__ float fast_exp(float x) {
  return __builtin_amdgcn_exp2f(x * 1.44269504088896f);
}
// LDS-only barrier: does NOT drain vmcnt -> global loads/stores stay in flight.
__device__ __forceinline__ void lds_barrier() {
  asm volatile("s_waitcnt lgkmcnt(0)\n\ts_barrier" ::: "memory");
}
// Single-wave LDS write->read fence.
__device__ __forceinline__ void lds_fence() {
  asm volatile("s_waitcnt lgkmcnt(0)" ::: "memory");
}
__device__ __forceinline__ half2_t cvt_pk(float a, float b) {
  return __builtin_bit_cast(half2_t, __builtin_amdgcn_cvt_pkrtz(a, b));
}
__device__ __forceinline__ half2_t h2bc(float v) {
  _Float16 h = (_Float16)v;
  half2_t r; r[0] = h; r[1] = h;
  return r;
}
__device__ __forceinline__ half8_t h8bc(float v) {
  _Float16 h = (_Float16)v;
  half8_t r;
#pragma unroll
  for (int i = 0; i < 8; ++i) r[i] = h;
  return r;
}
// max over the 4 quads (lane bits 4,5) for each n16 column — pure VALU (permlane swaps)
__device__ __forceinline__ float quad_max4(float v) {
  unsigned a = __builtin_bit_cast(unsigned, v);
  uint2_t r = __builtin_amdgcn_permlane32_swap(a, a, false, false);
  float m = fmaxf(__builtin_bit_cast(float, r[0]), __builtin_bit_cast(float, r[1]));
  unsigned b = __builtin_bit_cast(unsigned, m);
  uint2_t s = __builtin_amdgcn_permlane16_swap(b, b, false, false);
  return fmaxf(__builtin_bit_cast(float, s[0]), __builtin_bit_cast(float, s[1]));
}
// deg-5 odd tanh poly (fit at 1, 1.6; clamp +-1.6): 6 pk instrs
__device__ __forceinline__ half2_t tanh6(half2_t x) {
  half2_t y = __builtin_elementwise_min(__builtin_elementwise_max(x, h2bc(-1.6f)), h2bc(1.6f));
  half2_t u = y * y;
  half2_t p = u * h2bc(0.04667f) + h2bc(-0.28507f);
  p = u * p + h2bc(1.0f);
  return y * p;
}
// sigmoid, x/2 folded into coefficients: 6 pk instrs
__device__ __forceinline__ half2_t sig6(half2_t x) {
  half2_t y = __builtin_elementwise_min(__builtin_elementwise_max(x, h2bc(-3.2f)), h2bc(3.2f));
  half2_t u = y * y;
  half2_t q = u * h2bc(0.00072921875f) + h2bc(-0.017816875f);
  q = u * q + h2bc(0.25f);
  return y * q + h2bc(0.5f);
}

// ---------------------------------------------------------------- init + embed (fused, independent)
// Also zeroes out[0] each replay (merge accumulates into it atomically).
__global__ __launch_bounds__(256) void initembed_kernel(const int* __restrict__ kmers,
                                                        const float* __restrict__ emb,
                                                        half4_t* __restrict__ x,
                                                        float4_t* __restrict__ state,
                                                        float* __restrict__ out) {
  if (blockIdx.x < 48) {
    if (blockIdx.x == 0 && threadIdx.x == 0) out[0] = 0.f;
    state[blockIdx.x * 256 + threadIdx.x] = (float4_t){0.f, 0.f, 0.f, 0.f};
    return;
  }
  const int g = (blockIdx.x - 48) * 256 + threadIdx.x;
  const int row = g >> 5, seg = g & 31;
  const int km = kmers[row];
  const float4_t v = ((const float4_t*)(emb + (size_t)km * EE))[seg];
  half4_t o;
  o[0] = (_Float16)v[0]; o[1] = (_Float16)v[1];
  o[2] = (_Float16)v[2]; o[3] = (_Float16)v[3];
  x[(size_t)row * 32 + seg] = o;
}

// ---------------------------------------------------------------- xg body (device)
// Orientation: A = W_ih (regs), B = x^T (b128 global loads), C rows=hu-part, col=batch.
__device__ __forceinline__ void xg_body(
    int wg, int tid, const _Float16* __restrict__ x,
    const float* __restrict__ w_ih_f, const float* __restrict__ b_ih_f, const float* __restrict__ b_hh_f,
    const float* __restrict__ w_ih_b, const float* __restrict__ b_ih_b, const float* __restrict__ b_hh_b,
    _Float16* __restrict__ xgbuf, int s, int Tseg) {
  const int nt = Tseg >> 4;
  const int dir = wg / (8 * nt);
  const int rem = wg - dir * 8 * nt;
  const int chunk = rem / nt;
  const int tb = rem - chunk * nt;
  const int wave = tid >> 6, lane = tid & 63;
  const int n16 = lane & 15, quad = lane >> 4;

  const float* wih = dir ? w_ih_b : w_ih_f;
  const float* bih = dir ? b_ih_b : b_ih_f;
  const float* bhh = dir ? b_hh_b : b_hh_f;

  half8_t wf[4][4];
#pragma unroll
  for (int g = 0; g < 4; ++g) {
    const int row = g * HH + wave * 16 + n16;
#pragma unroll
    for (int kf = 0; kf < 4; ++kf) {
      const float* src = wih + row * EE + kf * 32 + quad * 8;
#pragma unroll
      for (int i = 0; i < 8; ++i) wf[g][kf][i] = (_Float16)src[i];
    }
  }
  float4_t bias4[4];
#pragma unroll
  for (int g = 0; g < 4; ++g) {
    const int row = g * HH + wave * 16 + quad * 4;
    const float4_t bi = *(const float4_t*)(bih + row);
    const float4_t bh = *(const float4_t*)(bhh + row);
    bias4[g] = bi + bh;
  }

  const int l0 = tb * 16;
  half8_t xb[4];
  {
    const int te = dir ? (TT - 1 - (s * Tseg + l0)) : (s * Tseg + l0);
#pragma unroll
    for (int kf = 0; kf < 4; ++kf)
      xb[kf] = *(const half8_t*)(x + ((size_t)te * BB + chunk * 16 + n16) * EE + kf * 32 + quad * 8);
  }
  for (int u = 0; u < 16; ++u) {
    const int l = l0 + u;
    half8_t xn[4] = {};
    if (u < 15) {
      const int tn = dir ? (TT - 1 - (s * Tseg + l + 1)) : (s * Tseg + l + 1);
#pragma unroll
      for (int kf = 0; kf < 4; ++kf)
        xn[kf] = *(const half8_t*)(x + ((size_t)tn * BB + chunk * 16 + n16) * EE + kf * 32 + quad * 8);
    }
    float4_t acc[4];
#pragma unroll
    for (int g = 0; g < 4; ++g) acc[g] = bias4[g];
#pragma unroll
    for (int kf = 0; kf < 4; ++kf)
#pragma unroll
      for (int g = 0; g < 4; ++g)
        acc[g] = __builtin_amdgcn_mfma_f32_16x16x32_f16(wf[g][kf], xb[kf], acc[g], 0, 0, 0);
    half8_t ho0, ho1;
#pragma unroll
    for (int r = 0; r < 4; ++r) {
      ho0[r] = (_Float16)acc[0][r];
      ho0[4 + r] = (_Float16)acc[1][r];
      ho1[r] = (_Float16)acc[2][r];
      ho1[4 + r] = (_Float16)acc[3][r];
    }
    _Float16* ob = xgbuf + (size_t)dir * Tseg * 65536 + (size_t)l * 65536 + chunk * 8192 +
                   wave * 1024 + lane * 16;
    *(half8_t*)ob = ho0;
    *(half8_t*)(ob + 8) = ho1;
#pragma unroll
    for (int kf = 0; kf < 4; ++kf) xb[kf] = xn[kf];
  }
}

// ---------------------------------------------------------------- standalone xg (first segment)
__global__ __launch_bounds__(512) void xg_kernel(
    const _Float16* __restrict__ x,
    const float* __restrict__ w_ih_f, const float* __restrict__ b_ih_f, const float* __restrict__ b_hh_f,
    const float* __restrict__ w_ih_b, const float* __restrict__ b_ih_b, const float* __restrict__ b_hh_b,
    _Float16* __restrict__ xgbuf, int s, int Tseg) {
  xg_body(blockIdx.x, threadIdx.x, x, w_ih_f, b_ih_f, b_hh_f, w_ih_b, b_ih_b, b_hh_b, xgbuf, s,
          Tseg);
}

// ---------------------------------------------------------------- fused: lstm(s) + xg(s+1)
// R4/R6-proven 512-thread structure (162.7 us/dispatch, VGPR 76): blocks 0..15 = one
// (dir,chunk) LSTM chain each (8 waves); blocks 16+ = one xg unit each. LSTM_STEP is the
// exact R6 4-deep chained accumulation — R10's 2-deep split REGRESSED (+9%, VGPR 76->84):
// the step is issue-bound, so extra accumulators + adds cost more than the dep latency saved.
// R7-R9: 1024-thread blocks are pinned to a 64-VGPR cap by this toolchain (spills); don't.
__global__ __launch_bounds__(512, 2) void lstm_xg_kernel(
    const _Float16* __restrict__ xgrd, _Float16* __restrict__ xgwr,
    const _Float16* __restrict__ x,
    const float* __restrict__ w_hh_f, const float* __restrict__ w_hh_b,
    const float* __restrict__ w_ih_f, const float* __restrict__ b_ih_f, const float* __restrict__ b_hh_f,
    const float* __restrict__ w_ih_b, const float* __restrict__ b_ih_b, const float* __restrict__ b_hh_b,
    _Float16* __restrict__ h_cat, _Float16* __restrict__ h_state, float* __restrict__ c_state,
    int s, int sx, int Tseg) {
  __shared__ _Float16 A[2][16 * ASTR];
  if (blockIdx.x >= 16) {
    xg_body(blockIdx.x - 16, threadIdx.x, x, w_ih_f, b_ih_f, b_hh_f, w_ih_b, b_ih_b, b_hh_b,
            xgwr, sx, Tseg);
    return;
  }
  const int wg = blockIdx.x;
  const int dir = wg >> 3, chunk = wg & 7;
  const int b0 = chunk * 16;
  const float* w_hh = dir ? w_hh_b : w_hh_f;
  const int tid = threadIdx.x;
  const int wave = tid >> 6, lane = tid & 63;
  const int n16 = lane & 15, quad = lane >> 4;

  half8_t wf[4][4];
#pragma unroll
  for (int g = 0; g < 4; ++g) {
    const int row = g * HH + wave * 16 + n16;
#pragma unroll
    for (int kf = 0; kf < 4; ++kf) {
      const float* src = w_hh + row * HH + kf * 32 + quad * 8;
#pragma unroll
      for (int i = 0; i < 8; ++i) wf[g][kf][i] = (_Float16)src[i];
    }
  }
  // persistent state: layout identical to R5 ((dir*8+chunk)*8+wave)
  const int sidx = ((wg * 8 + wave) * 64 + lane) * 4;
  half4_t h4 = *(const half4_t*)(h_state + sidx);
  float4_t c4 = *(const float4_t*)(c_state + sidx);
  half2_t c2[2];
  c2[0] = cvt_pk(c4[0], c4[1]);
  c2[1] = cvt_pk(c4[2], c4[3]);
  *(half4_t*)(&A[0][n16 * ASTR + wave * 16 + quad * 4]) = h4;  // seed h_{-1}

  const _Float16* xgw =
      xgrd + (size_t)dir * Tseg * 65536 + chunk * 8192 + wave * 1024 + (size_t)lane * 16;
  half4_t hlast = h4;
  const float4_t z4 = {0.f, 0.f, 0.f, 0.f};
  const int te0 = dir ? (TT - 1 - s * Tseg) : (s * Tseg);
  _Float16* gp_run =
      h_cat + ((size_t)te0 * BB + b0 + n16) * 256 + dir * HH + wave * 16 + quad * 4;
  const ptrdiff_t dstep = dir ? -(ptrdiff_t)32768 : (ptrdiff_t)32768;

  // 4-deep in-place xg prefetch ring (static indices)
  half8_t pf0[4], pf1[4];
#pragma unroll
  for (int j = 0; j < 4; ++j) {
    const _Float16* p = xgw + (size_t)j * 65536;
    pf0[j] = *(const half8_t*)p;
    pf1[j] = *(const half8_t*)(p + 8);
  }

#define LSTM_STEP(AB, AN, X0, X1)                                                          \
  {                                                                                        \
    const _Float16* Abp = &AB[0];                                                          \
    _Float16* Anp = &AN[0];                                                                \
    half8_t hb0 = *(const half8_t*)(Abp + n16 * ASTR + 0 * 32 + quad * 8);                 \
    half8_t hb1 = *(const half8_t*)(Abp + n16 * ASTR + 1 * 32 + quad * 8);                 \
    half8_t hb2 = *(const half8_t*)(Abp + n16 * ASTR + 2 * 32 + quad * 8);                 \
    half8_t hb3 = *(const half8_t*)(Abp + n16 * ASTR + 3 * 32 + quad * 8);                 \
    float4_t acc[4];                                                                       \
    _Pragma("unroll") for (int g = 0; g < 4; ++g) {                                        \
      acc[g] = __builtin_amdgcn_mfma_f32_16x16x32_f16(wf[g][0], hb0, z4, 0, 0, 0);         \
    }                                                                                      \
    _Pragma("unroll") for (int g = 0; g < 4; ++g) {                                        \
      acc[g] = __builtin_amdgcn_mfma_f32_16x16x32_f16(wf[g][1], hb1, acc[g], 0, 0, 0);     \
    }                                                                                      \
    _Pragma("unroll") for (int g = 0; g < 4; ++g) {                                        \
      acc[g] = __builtin_amdgcn_mfma_f32_16x16x32_f16(wf[g][2], hb2, acc[g], 0, 0, 0);     \
    }                                                                                      \
    _Pragma("unroll") for (int g = 0; g < 4; ++g) {                                        \
      acc[g] = __builtin_amdgcn_mfma_f32_16x16x32_f16(wf[g][3], hb3, acc[g], 0, 0, 0);     \
    }                                                                                      \
    const half2_t* x0p = (const half2_t*)&X0;                                              \
    const half2_t* x1p = (const half2_t*)&X1;                                              \
    half4_t hstore;                                                                        \
    _Pragma("unroll") for (int p = 0; p < 2; ++p) {                                        \
      const half2_t i_ = sig6(cvt_pk(acc[0][2 * p], acc[0][2 * p + 1]) + x0p[p]);          \
      const half2_t f_ = sig6(cvt_pk(acc[1][2 * p], acc[1][2 * p + 1]) + x0p[2 + p]);      \
      const half2_t g_ = tanh6(cvt_pk(acc[2][2 * p], acc[2][2 * p + 1]) + x1p[p]);         \
      const half2_t o_ = sig6(cvt_pk(acc[3][2 * p], acc[3][2 * p + 1]) + x1p[2 + p]);      \
      c2[p] = f_ * c2[p] + i_ * g_;                                                        \
      const half2_t hh = o_ * tanh6(c2[p]);                                                \
      hstore[2 * p] = hh[0];                                                               \
      hstore[2 * p + 1] = hh[1];                                                           \
    }                                                                                      \
    *(half4_t*)(Anp + n16 * ASTR + wave * 16 + quad * 4) = hstore;                         \
    *(half4_t*)gp_run = hstore;                                                            \
    hlast = hstore;                                                                        \
  }

  // main loop: prefetch il+j+4 <= Tseg-1, no clamp needed
  for (int il = 0; il < Tseg - 4; il += 4) {
#pragma unroll
    for (int j = 0; j < 4; ++j) {
      lds_barrier();
      if (j & 1) {
        LSTM_STEP(A[1], A[0], pf0[j], pf1[j]);
      } else {
        LSTM_STEP(A[0], A[1], pf0[j], pf1[j]);
      }
      const _Float16* p = xgw + (size_t)(il + j + 4) * 65536;
      pf0[j] = *(const half8_t*)p;
      pf1[j] = *(const half8_t*)(p + 8);
      gp_run += dstep;
    }
  }
  // tail: last 4 steps, no prefetch
#pragma unroll
  for (int j = 0; j < 4; ++j) {
    lds_barrier();
    if (j & 1) {
      LSTM_STEP(A[1], A[0], pf0[j], pf1[j]);
    } else {
      LSTM_STEP(A[0], A[1], pf0[j], pf1[j]);
    }
    gp_run += dstep;
  }
#undef LSTM_STEP

  *(half4_t*)(h_state + sidx) = hlast;
  c4[0] = (float)c2[0][0]; c4[1] = (float)c2[0][1];
  c4[2] = (float)c2[1][0]; c4[3] = (float)c2[1][1];
  *(float4_t*)(c_state + sidx) = c4;
}

// ---------------------------------------------------------------- emissions: em f32 + expem f16
__global__ __launch_bounds__(256) void emis_kernel(const _Float16* __restrict__ h_cat,
                                                   const float* __restrict__ w_proj,
                                                   const float* __restrict__ b_proj,
                                                   float* __restrict__ em,
                                                   _Float16* __restrict__ expem) {
  const int tid = threadIdx.x;
  const int wave = tid >> 6, lane = tid & 63;
  const int n16 = lane & 15, quad = lane >> 4;
  const size_t row0 = (size_t)blockIdx.x * 64 + wave * 16;

  half8_t bf[4][8];
#pragma unroll
  for (int nt = 0; nt < 4; ++nt) {
    const float* wp = w_proj + (nt * 16 + n16) * 256;
#pragma unroll
    for (int kf = 0; kf < 8; ++kf) {
      const int kb = kf * 32 + quad * 8;
#pragma unroll
      for (int i = 0; i < 8; ++i) bf[nt][kf][i] = (_Float16)wp[kb + i];
    }
  }
  float4_t acc[4];
#pragma unroll
  for (int nt = 0; nt < 4; ++nt) {
    const float bv = b_proj[nt * 16 + n16];
    acc[nt] = (float4_t){bv, bv, bv, bv};
  }
#pragma unroll
  for (int kf = 0; kf < 8; ++kf) {
    half8_t af = *(const half8_t*)(h_cat + (row0 + n16) * 256 + kf * 32 + quad * 8);
#pragma unroll
    for (int nt = 0; nt < 4; ++nt)
      acc[nt] = __builtin_amdgcn_mfma_f32_16x16x32_f16(af, bf[nt][kf], acc[nt], 0, 0, 0);
  }
#pragma unroll
  for (int nt = 0; nt < 4; ++nt)
#pragma unroll
    for (int r = 0; r < 4; ++r) {
      const size_t idx = (row0 + quad * 4 + r) * NTAG + nt * 16 + n16;
      em[idx] = acc[nt][r];
      expem[idx] = (_Float16)fast_exp(acc[nt][r]);
    }
}

// ---------------------------------------------------------------- segment-parallel CRF matrices
// 2048 chains (128 batches x 16 segments), 1 wave each: N <- diag(g_t) (E^T N), N init = I.
// Stored as Nbuf[b][s][c][k] = N[k][c] = P_s[c][k]. Blocks >= 2048: CRF numerator.
__global__ __launch_bounds__(64) void mcrf_kernel(const float* __restrict__ em,
                                                  const _Float16* __restrict__ expem,
                                                  const float* __restrict__ trans,
                                                  const int* __restrict__ tags,
                                                  const float* __restrict__ start_trans,
                                                  const float* __restrict__ end_trans,
                                                  _Float16* __restrict__ Nbuf,
                                                  float* __restrict__ lzbuf,
                                                  float* __restrict__ num) {
  const int lane = threadIdx.x;
  if (blockIdx.x >= 2048) {  // ---------------- numerator (1 wave per batch)
    const int nb = blockIdx.x - 2048;
    const int tg = tags[nb];
    float acc = 0.f;
    for (int t = lane; t < TT; t += 64)
      acc += em[((size_t)t * BB + nb) * NTAG + tg];
#pragma unroll
    for (int off = 32; off > 0; off >>= 1) acc += __shfl_xor(acc, off, 64);
    if (lane == 0)
      num[nb] = start_trans[tg] + end_trans[tg] + 1023.0f * trans[tg * NTAG + tg] + acc;
    return;
  }
  const int n16 = lane & 15, quad = lane >> 4;
  const int b = blockIdx.x >> 4;
  const int s = blockIdx.x & 15;

  half8_t efA[4][2];
#pragma unroll
  for (int mt = 0; mt < 4; ++mt)
#pragma unroll
    for (int kf = 0; kf < 2; ++kf)
#pragma unroll
      for (int i = 0; i < 8; ++i) {
        const int m = mt * 16 + n16, k = kf * 32 + quad * 8 + i;
        efA[mt][kf][i] = (_Float16)(fast_exp(trans[k * NTAG + m]) * 0.015625f);
      }

  half8_t pb[4][2];
#pragma unroll
  for (int tile = 0; tile < 4; ++tile)
#pragma unroll
    for (int kf = 0; kf < 2; ++kf)
#pragma unroll
      for (int i = 0; i < 8; ++i) {
        const int k = kf * 32 + quad * 8 + i;
        pb[tile][kf][i] = (_Float16)((k == tile * 16 + n16) ? 1.f : 0.f);
      }

  float lz2 = 0.f;
  const float4_t z4 = {0.f, 0.f, 0.f, 0.f};
  const _Float16* exb = expem + (size_t)b * NTAG;
  const int t0 = s * 64 + 1;
  const int nsteps = (s == 15) ? 63 : 64;

#define MCRF_CORE(PB0, PB1, NB0, NB1)                                                      \
  {                                                                                        \
    float4_t a0 = __builtin_amdgcn_mfma_f32_16x16x32_f16(efA[0][0], PB0, z4, 0, 0, 0);     \
    float4_t a1 = __builtin_amdgcn_mfma_f32_16x16x32_f16(efA[1][0], PB0, z4, 0, 0, 0);     \
    float4_t a2 = __builtin_amdgcn_mfma_f32_16x16x32_f16(efA[2][0], PB0, z4, 0, 0, 0);     \
    float4_t a3 = __builtin_amdgcn_mfma_f32_16x16x32_f16(efA[3][0], PB0, z4, 0, 0, 0);     \
    a0 = __builtin_amdgcn_mfma_f32_16x16x32_f16(efA[0][1], PB1, a0, 0, 0, 0);              \
    a1 = __builtin_amdgcn_mfma_f32_16x16x32_f16(efA[1][1], PB1, a1, 0, 0, 0);              \
    a2 = __builtin_amdgcn_mfma_f32_16x16x32_f16(efA[2][1], PB1, a2, 0, 0, 0);              \
    a3 = __builtin_amdgcn_mfma_f32_16x16x32_f16(efA[3][1], PB1, a3, 0, 0, 0);              \
    half2_t dpk[4][2];                                                                     \
    dpk[0][0] = cvt_pk(a0[0], a0[1]); dpk[0][1] = cvt_pk(a0[2], a0[3]);                    \
    dpk[1][0] = cvt_pk(a1[0], a1[1]); dpk[1][1] = cvt_pk(a1[2], a1[3]);                    \
    dpk[2][0] = cvt_pk(a2[0], a2[1]); dpk[2][1] = cvt_pk(a2[2], a2[3]);                    \
    dpk[3][0] = cvt_pk(a3[0], a3[1]); dpk[3][1] = cvt_pk(a3[2], a3[3]);                    \
    half2_t* wwp0 = (half2_t*)&NB0;                                                        \
    half2_t* wwp1 = (half2_t*)&NB1;                                                        \
    _Pragma("unroll") for (int kf = 0; kf < 2; ++kf) {                                     \
      half2_t* wp = kf ? wwp1 : wwp0;                                                      \
      _Pragma("unroll") for (int p = 0; p < 2; ++p) {                                      \
        const unsigned Xu = __builtin_bit_cast(unsigned, dpk[2 * kf][p]);                  \
        const unsigned Yu = __builtin_bit_cast(unsigned, dpk[2 * kf + 1][p]);              \
        uint2_t r1 = __builtin_amdgcn_permlane32_swap(Xu, Yu, false, false);               \
        uint2_t r2 = __builtin_amdgcn_permlane16_swap(r1[0], r1[1], false, false);         \
        wp[p] = __builtin_bit_cast(half2_t, r2[0]);                                        \
        wp[2 + p] = __builtin_bit_cast(half2_t, r2[1]);                                    \
      }                                                                                    \
    }                                                                                      \
  }

#define MSTEP(GC0, GC1, IT)                                                                \
  {                                                                                        \
    _Pragma("unroll") for (int tile = 0; tile < 4; ++tile) {                               \
      half8_t nb0, nb1;                                                                    \
      MCRF_CORE(pb[tile][0], pb[tile][1], nb0, nb1)                                        \
      pb[tile][0] = nb0 * GC0;                                                             \
      pb[tile][1] = nb1 * GC1;                                                             \
    }                                                                                      \
    if (((IT) & 15) == 15) {                                                               \
      half8_t m8 = __builtin_elementwise_max(pb[0][0], pb[0][1]);                          \
      m8 = __builtin_elementwise_max(m8, __builtin_elementwise_max(pb[1][0], pb[1][1]));   \
      m8 = __builtin_elementwise_max(m8, __builtin_elementwise_max(pb[2][0], pb[2][1]));   \
      m8 = __builtin_elementwise_max(m8, __builtin_elementwise_max(pb[3][0], pb[3][1]));   \
      float mm = (float)m8[0];                                                             \
      _Pragma("unroll") for (int i = 1; i < 8; ++i) mm = fmaxf(mm, (float)m8[i]);          \
      mm = quad_max4(mm);                                                                  \
      mm = fmaxf(mm, __shfl_xor(mm, 1, 64));                                               \
      mm = fmaxf(mm, __shfl_xor(mm, 2, 64));                                               \
      mm = fmaxf(mm, __shfl_xor(mm, 4, 64));                                               \
      mm = fmaxf(mm, __shfl_xor(mm, 8, 64));                                               \
      lz2 += __builtin_amdgcn_logf(mm);                                                    \
      const half8_t rc8 = h8bc(__builtin_amdgcn_rcpf(mm));                                 \
      _Pragma("unroll") for (int tile = 0; tile < 4; ++tile) {                             \
        pb[tile][0] *= rc8;                                                                \
        pb[tile][1] *= rc8;                                                                \
      }                                                                                    \
    }                                                                                      \
  }

  half8_t pre0[4], pre1[4];
#pragma unroll
  for (int j = 0; j < 4; ++j) {
    const size_t tt = (size_t)(t0 + j) * 8192;
    pre0[j] = *(const half8_t*)(exb + tt + quad * 8);
    pre1[j] = *(const half8_t*)(exb + tt + 32 + quad * 8);
  }
  int it = 0;
  const int full4 = nsteps >> 2;
  for (int grp = 0; grp < full4; ++grp) {
#pragma unroll
    for (int j = 0; j < 4; ++j) {
      const half8_t gc0 = pre0[j], gc1 = pre1[j];
      int tf = t0 + it + 4;
      tf = tf > 1023 ? 1023 : tf;
      const size_t tt = (size_t)tf * 8192;
      pre0[j] = *(const half8_t*)(exb + tt + quad * 8);
      pre1[j] = *(const half8_t*)(exb + tt + 32 + quad * 8);
      MSTEP(gc0, gc1, it)
      ++it;
    }
  }
  for (; it < nsteps; ++it) {
    const size_t tt = (size_t)(t0 + it) * 8192;
    const half8_t gc0 = *(const half8_t*)(exb + tt + quad * 8);
    const half8_t gc1 = *(const half8_t*)(exb + tt + 32 + quad * 8);
    MSTEP(gc0, gc1, it)
  }
#undef MSTEP
#undef MCRF_CORE

  _Float16* nb = Nbuf + ((size_t)b * 16 + s) * 4096;
#pragma unroll
  for (int tile = 0; tile < 4; ++tile) {
    const int col = tile * 16 + n16;
#pragma unroll
    for (int kf = 0; kf < 2; ++kf)
      *(half8_t*)(nb + (size_t)col * 64 + kf * 32 + quad * 8) = pb[tile][kf];
  }
  if (lane == 0) lzbuf[b * 16 + s] = lz2;
}

// ---------------------------------------------------------------- merge: w <- P_s w, alpha0 dot,
// then atomically accumulate (denom_b - num_b) into out[0] (zeroed by initembed each replay).
__global__ __launch_bounds__(64) void merge_kernel(const _Float16* __restrict__ Nbuf,
                                                   const float* __restrict__ lzbuf,
                                                   const float* __restrict__ em,
                                                   const float* __restrict__ start_trans,
                                                   const float* __restrict__ end_trans,
                                                   const float* __restrict__ num,
                                                   float* __restrict__ out) {
  const int b = blockIdx.x, m = threadIdx.x;
  __shared__ float w[64];
  float L2 = 0.f;
  w[m] = fast_exp(end_trans[m]);
  for (int s = 15; s >= 0; --s) {
    lds_fence();
    const _Float16* row = Nbuf + (((size_t)b * 16 + s) * 64 + m) * 64;
    float acc = 0.f;
#pragma unroll
    for (int kf = 0; kf < 8; ++kf) {
      const half8_t rv = *(const half8_t*)(row + kf * 8);
#pragma unroll
      for (int i = 0; i < 8; ++i) acc += (float)rv[i] * w[kf * 8 + i];
    }
    float mx = acc;
#pragma unroll
    for (int off = 32; off > 0; off >>= 1) mx = fmaxf(mx, __shfl_xor(mx, off, 64));
    L2 += __builtin_amdgcn_logf(mx) + lzbuf[b * 16 + s];
    const float inv = __builtin_amdgcn_rcpf(mx);
    lds_fence();
    w[m] = acc * inv;
  }
  lds_fence();
  const float sv = start_trans[m] + em[(size_t)b * NTAG + m];  // t=0 row
  float m0 = sv;
#pragma unroll
  for (int off = 32; off > 0; off >>= 1) m0 = fmaxf(m0, __shfl_xor(m0, off, 64));
  float z = fast_exp(sv - m0) * w[m];
#pragma unroll
  for (int off = 32; off > 0; off >>= 1) z += __shfl_xor(z, off, 64);
  if (m == 0) {
    const float denomv =
        m0 + 0.693147180559945f * (L2 + 6138.0f + __builtin_amdgcn_logf(z));
    atomicAdd(out, denomv - num[b]);
  }
}

extern "C" void kernel_launch(void* const* d_in, const int* in_sizes, int n_in,
                              void* d_out, int out_size, void* d_ws, size_t ws_size,
                              hipStream_t stream) {
  const int* kmers = (const int*)d_in[0];
  const int* tags = (const int*)d_in[1];
  const float* emb = (const float*)d_in[2];
  const float* w_ih_f = (const float*)d_in[3];
  const float* w_hh_f = (const float*)d_in[4];
  const float* b_ih_f = (const float*)d_in[5];
  const float* b_hh_f = (const float*)d_in[6];
  const float* w_ih_b = (const float*)d_in[7];
  const float* w_hh_b = (const float*)d_in[8];
  const float* b_ih_b = (const float*)d_in[9];
  const float* b_hh_b = (const float*)d_in[10];
  const float* w_proj = (const float*)d_in[11];
  const float* b_proj = (const float*)d_in[12];
  const float* start_trans = (const float*)d_in[13];
  const float* end_trans = (const float*)d_in[14];
  const float* trans = (const float*)d_in[15];

  char* ws = (char*)d_ws;
  half4_t* x = (half4_t*)ws;                       // [0, 33.5M); em aliases after xg done
  _Float16* h_cat = (_Float16*)(ws + 33554432);    // [33.5M, 100.7M)
  float* em = (float*)ws;
  float* out = (float*)d_out;
  // post-emis overlays of the dead h_cat region (path-independent):
  _Float16* Nbuf = (_Float16*)(ws + 33554432);            // 16.8 MB
  float* lzbuf = (float*)(ws + 33554432 + 16777216);      // 8 KB
  float* num = (float*)(ws + 33554432 + 16785920);        // 512 B

  const bool fused = ws_size >= 235078656ull;
  if (fused) {
    const int Tseg = 256;
    _Float16* buf0 = (_Float16*)(ws + 100663296);              // 64 MB
    _Float16* buf1 = (_Float16*)(ws + 100663296 + 67108864);   // 64 MB
    _Float16* expem = (_Float16*)(ws + 100663296);             // aliases buf0 (dead after lstm)
    _Float16* h_state = (_Float16*)(ws + 100663296 + 134217728);
    float* c_state = (float*)(ws + 100663296 + 134217728 + 65536);

    hipLaunchKernelGGL(initembed_kernel, dim3(16432), dim3(256), 0, stream, kmers, emb, x,
                       (float4_t*)h_state, out);
    hipLaunchKernelGGL(xg_kernel, dim3(Tseg), dim3(512), 0, stream, (const _Float16*)x,
                       w_ih_f, b_ih_f, b_hh_f, w_ih_b, b_ih_b, b_hh_b, buf0, 0, Tseg);
    for (int s = 0; s < 3; ++s) {
      _Float16* rd = (s & 1) ? buf1 : buf0;
      _Float16* wr = (s & 1) ? buf0 : buf1;
      hipLaunchKernelGGL(lstm_xg_kernel, dim3(16 + Tseg), dim3(512), 0, stream,
                         (const _Float16*)rd, wr, (const _Float16*)x, w_hh_f, w_hh_b,
                         w_ih_f, b_ih_f, b_hh_f, w_ih_b, b_ih_b, b_hh_b,
                         h_cat, h_state, c_state, s, s + 1, Tseg);
    }
    hipLaunchKernelGGL(lstm_xg_kernel, dim3(16), dim3(512), 0, stream,
                       (const _Float16*)buf1, buf0, (const _Float16*)x, w_hh_f, w_hh_b,
                       w_ih_f, b_ih_f, b_hh_f, w_ih_b, b_ih_b, b_hh_b,
                       h_cat, h_state, c_state, 3, 0, Tseg);
    hipLaunchKernelGGL(emis_kernel, dim3(2048), dim3(256), 0, stream, h_cat, w_proj, b_proj, em,
                       expem);
    hipLaunchKernelGGL(mcrf_kernel, dim3(2176), dim3(64), 0, stream, em,
                       (const _Float16*)expem, trans, tags, start_trans, end_trans, Nbuf, lzbuf,
                       num);
    hipLaunchKernelGGL(merge_kernel, dim3(128), dim3(64), 0, stream, (const _Float16*)Nbuf,
                       lzbuf, em, start_trans, end_trans, num, out);
  } else {
    int nseg;
    if (ws_size >= 167969792ull) nseg = 4;
    else if (ws_size >= 134415360ull) nseg = 8;
    else nseg = 16;
    const int Tseg = TT / nseg;
    const size_t xg_bytes = 268435456ull / (size_t)nseg;
    _Float16* xgbuf = (_Float16*)(ws + 100663296);
    _Float16* expem = (_Float16*)(ws + 100663296);
    _Float16* h_state = (_Float16*)(ws + 100663296 + xg_bytes);
    float* c_state = (float*)(ws + 100663296 + xg_bytes + 65536);

    hipLaunchKernelGGL(initembed_kernel, dim3(16432), dim3(256), 0, stream, kmers, emb, x,
                       (float4_t*)h_state, out);
    for (int s = 0; s < nseg; ++s) {
      hipLaunchKernelGGL(xg_kernel, dim3(Tseg), dim3(512), 0, stream, (const _Float16*)x,
                         w_ih_f, b_ih_f, b_hh_f, w_ih_b, b_ih_b, b_hh_b, xgbuf, s, Tseg);
      hipLaunchKernelGGL(lstm_xg_kernel, dim3(16), dim3(512), 0, stream,
                         (const _Float16*)xgbuf, xgbuf, (const _Float16*)x, w_hh_f, w_hh_b,
                         w_ih_f, b_ih_f, b_hh_f, w_ih_b, b_ih_b, b_hh_b,
                         h_cat, h_state, c_state, s, s, Tseg);
    }
    hipLaunchKernelGGL(emis_kernel, dim3(2048), dim3(256), 0, stream, h_cat, w_proj, b_proj, em,
                       expem);
    hipLaunchKernelGGL(mcrf_kernel, dim3(2176), dim3(64), 0, stream, em,
                       (const _Float16*)expem, trans, tags, start_trans, end_trans, Nbuf, lzbuf,
                       num);
    hipLaunchKernelGGL(merge_kernel, dim3(128), dim3(64), 0, stream, (const _Float16*)Nbuf,
                       lzbuf, em, start_trans, end_trans, num, out);
  }
}

// Round 12
// 930.120 us; speedup vs baseline: 3.4024x; 1.0298x over previous
//
#include <hip/hip_runtime.h>
#include <hip/hip_bf16.h>

typedef _Float16 half8_t __attribute__((ext_vector_type(8)));
typedef _Float16 half4_t __attribute__((ext_vector_type(4)));
typedef _Float16 half2_t __attribute__((ext_vector_type(2)));
typedef float float4_t __attribute__((ext_vector_type(4)));
typedef unsigned int uint2_t __attribute__((ext_vector_type(2)));

#define TT 1024
#define BB 128
#define EE 128
#define HH 128
#define NTAG 64
#define ASTR 144  // [batch][hu] LDS panel stride (f16) — R6-proven for the b128 read pattern

__device__ __forceinline__ float fast_exp(float x) {
  return __builtin_amdgcn_exp2f(x * 1.44269504088896f);
}
// LDS-only barrier: does NOT drain vmcnt -> global loads/stores stay in flight.
__device__ __forceinline__ void lds_barrier() {
  asm volatile("s_waitcnt lgkmcnt(0)\n\ts_barrier" ::: "memory");
}
// Single-wave LDS write->read fence.
__device__ __forceinline__ void lds_fence() {
  asm volatile("s_waitcnt lgkmcnt(0)" ::: "memory");
}
__device__ __forceinline__ half2_t cvt_pk(float a, float b) {
  return __builtin_bit_cast(half2_t, __builtin_amdgcn_cvt_pkrtz(a, b));
}
__device__ __forceinline__ half2_t h2bc(float v) {
  _Float16 h = (_Float16)v;
  half2_t r; r[0] = h; r[1] = h;
  return r;
}
__device__ __forceinline__ half8_t h8bc(float v) {
  _Float16 h = (_Float16)v;
  half8_t r;
#pragma unroll
  for (int i = 0; i < 8; ++i) r[i] = h;
  return r;
}
// max over the 4 quads (lane bits 4,5) for each n16 column — pure VALU (permlane swaps)
__device__ __forceinline__ float quad_max4(float v) {
  unsigned a = __builtin_bit_cast(unsigned, v);
  uint2_t r = __builtin_amdgcn_permlane32_swap(a, a, false, false);
  float m = fmaxf(__builtin_bit_cast(float, r[0]), __builtin_bit_cast(float, r[1]));
  unsigned b = __builtin_bit_cast(unsigned, m);
  uint2_t s = __builtin_amdgcn_permlane16_swap(b, b, false, false);
  return fmaxf(__builtin_bit_cast(float, s[0]), __builtin_bit_cast(float, s[1]));
}
// deg-5 odd tanh poly (fit at 1, 1.6; clamp +-1.6): 6 pk instrs
__device__ __forceinline__ half2_t tanh6(half2_t x) {
  half2_t y = __builtin_elementwise_min(__builtin_elementwise_max(x, h2bc(-1.6f)), h2bc(1.6f));
  half2_t u = y * y;
  half2_t p = u * h2bc(0.04667f) + h2bc(-0.28507f);
  p = u * p + h2bc(1.0f);
  return y * p;
}
// sigmoid, x/2 folded into coefficients: 6 pk instrs
__device__ __forceinline__ half2_t sig6(half2_t x) {
  half2_t y = __builtin_elementwise_min(__builtin_elementwise_max(x, h2bc(-3.2f)), h2bc(3.2f));
  half2_t u = y * y;
  half2_t q = u * h2bc(0.00072921875f) + h2bc(-0.017816875f);
  q = u * q + h2bc(0.25f);
  return y * q + h2bc(0.5f);
}
// gather one 8-f32 slice of emb and convert RNE (identical numerics to old initembed)
__device__ __forceinline__ half8_t emb8(const float* __restrict__ p) {
  const float4_t lo = *(const float4_t*)p;
  const float4_t hi = *(const float4_t*)(p + 4);
  half8_t v;
  v[0] = (_Float16)lo[0]; v[1] = (_Float16)lo[1];
  v[2] = (_Float16)lo[2]; v[3] = (_Float16)lo[3];
  v[4] = (_Float16)hi[0]; v[5] = (_Float16)hi[1];
  v[6] = (_Float16)hi[2]; v[7] = (_Float16)hi[3];
  return v;
}

// ---------------------------------------------------------------- xg body (device)
// Orientation: A = W_ih (regs), B = x^T (inline emb gather, f32->f16 RNE), C rows=hu-part.
// The 33.5MB x buffer + initembed launch are gone: emb (33.5MB) is L3-resident so per-step
// gathers are cheap, and xg runs on CUs that are otherwise idle under the lstm chain.
__device__ __forceinline__ void xg_body(
    int wg, int tid, const int* __restrict__ kmers, const float* __restrict__ emb,
    const float* __restrict__ w_ih_f, const float* __restrict__ b_ih_f, const float* __restrict__ b_hh_f,
    const float* __restrict__ w_ih_b, const float* __restrict__ b_ih_b, const float* __restrict__ b_hh_b,
    _Float16* __restrict__ xgbuf, int s, int Tseg) {
  const int nt = Tseg >> 4;
  const int dir = wg / (8 * nt);
  const int rem = wg - dir * 8 * nt;
  const int chunk = rem / nt;
  const int tb = rem - chunk * nt;
  const int wave = tid >> 6, lane = tid & 63;
  const int n16 = lane & 15, quad = lane >> 4;

  const float* wih = dir ? w_ih_b : w_ih_f;
  const float* bih = dir ? b_ih_b : b_ih_f;
  const float* bhh = dir ? b_hh_b : b_hh_f;

  half8_t wf[4][4];
#pragma unroll
  for (int g = 0; g < 4; ++g) {
    const int row = g * HH + wave * 16 + n16;
#pragma unroll
    for (int kf = 0; kf < 4; ++kf) {
      const float* src = wih + row * EE + kf * 32 + quad * 8;
#pragma unroll
      for (int i = 0; i < 8; ++i) wf[g][kf][i] = (_Float16)src[i];
    }
  }
  float4_t bias4[4];
#pragma unroll
  for (int g = 0; g < 4; ++g) {
    const int row = g * HH + wave * 16 + quad * 4;
    const float4_t bi = *(const float4_t*)(bih + row);
    const float4_t bh = *(const float4_t*)(bhh + row);
    bias4[g] = bi + bh;
  }

  const int bidx = chunk * 16 + n16;
  const int l0 = tb * 16;
  half8_t xb[4];
  {
    const int te = dir ? (TT - 1 - (s * Tseg + l0)) : (s * Tseg + l0);
    const int km = kmers[te * BB + bidx];
    const float* er = emb + (size_t)km * EE;
#pragma unroll
    for (int kf = 0; kf < 4; ++kf) xb[kf] = emb8(er + kf * 32 + quad * 8);
  }
  for (int u = 0; u < 16; ++u) {
    const int l = l0 + u;
    half8_t xn[4] = {};
    if (u < 15) {
      const int tn = dir ? (TT - 1 - (s * Tseg + l + 1)) : (s * Tseg + l + 1);
      const int kmn = kmers[tn * BB + bidx];
      const float* er = emb + (size_t)kmn * EE;
#pragma unroll
      for (int kf = 0; kf < 4; ++kf) xn[kf] = emb8(er + kf * 32 + quad * 8);
    }
    float4_t acc[4];
#pragma unroll
    for (int g = 0; g < 4; ++g) acc[g] = bias4[g];
#pragma unroll
    for (int kf = 0; kf < 4; ++kf)
#pragma unroll
      for (int g = 0; g < 4; ++g)
        acc[g] = __builtin_amdgcn_mfma_f32_16x16x32_f16(wf[g][kf], xb[kf], acc[g], 0, 0, 0);
    half8_t ho0, ho1;
#pragma unroll
    for (int r = 0; r < 4; ++r) {
      ho0[r] = (_Float16)acc[0][r];
      ho0[4 + r] = (_Float16)acc[1][r];
      ho1[r] = (_Float16)acc[2][r];
      ho1[4 + r] = (_Float16)acc[3][r];
    }
    _Float16* ob = xgbuf + (size_t)dir * Tseg * 65536 + (size_t)l * 65536 + chunk * 8192 +
                   wave * 1024 + lane * 16;
    *(half8_t*)ob = ho0;
    *(half8_t*)(ob + 8) = ho1;
#pragma unroll
    for (int kf = 0; kf < 4; ++kf) xb[kf] = xn[kf];
  }
}

// ---------------------------------------------------------------- emis unit (device, 256 thr)
// Low-register variant: w_proj frags loaded per-kf (bf[4] live, not bf[4][8]) -> ~60 VGPR,
// so it cannot cap the fused lstm_xg kernel's register budget.
__device__ __forceinline__ void emis_unit(int u, int tid, const _Float16* __restrict__ h_cat,
                                          const float* __restrict__ w_proj,
                                          const float* __restrict__ b_proj,
                                          float* __restrict__ em,
                                          _Float16* __restrict__ expem) {
  const int wave = tid >> 6, lane = tid & 63;
  const int n16 = lane & 15, quad = lane >> 4;
  const size_t row0 = (size_t)u * 64 + wave * 16;

  float4_t acc[4];
#pragma unroll
  for (int nt = 0; nt < 4; ++nt) {
    const float bv = b_proj[nt * 16 + n16];
    acc[nt] = (float4_t){bv, bv, bv, bv};
  }
#pragma unroll
  for (int kf = 0; kf < 8; ++kf) {
    const half8_t af = *(const half8_t*)(h_cat + (row0 + n16) * 256 + kf * 32 + quad * 8);
    const int kb = kf * 32 + quad * 8;
#pragma unroll
    for (int nt = 0; nt < 4; ++nt) {
      const float* wp = w_proj + (nt * 16 + n16) * 256 + kb;
      half8_t bf;
#pragma unroll
      for (int i = 0; i < 8; ++i) bf[i] = (_Float16)wp[i];
      acc[nt] = __builtin_amdgcn_mfma_f32_16x16x32_f16(af, bf, acc[nt], 0, 0, 0);
    }
  }
#pragma unroll
  for (int nt = 0; nt < 4; ++nt)
#pragma unroll
    for (int r = 0; r < 4; ++r) {
      const size_t idx = (row0 + quad * 4 + r) * NTAG + nt * 16 + n16;
      em[idx] = acc[nt][r];
      expem[idx] = (_Float16)fast_exp(acc[nt][r]);
    }
}

// ---------------------------------------------------------------- standalone xg (first segment)
// Blocks >= Tseg (present only in the s=0 launch): zero h_state/c_state (48 blocks) + out[0].
__global__ __launch_bounds__(512) void xg_kernel(
    const int* __restrict__ kmers, const float* __restrict__ emb,
    const float* __restrict__ w_ih_f, const float* __restrict__ b_ih_f, const float* __restrict__ b_hh_f,
    const float* __restrict__ w_ih_b, const float* __restrict__ b_ih_b, const float* __restrict__ b_hh_b,
    _Float16* __restrict__ xgbuf, int s, int Tseg,
    float4_t* __restrict__ zstate, float* __restrict__ out) {
  if (blockIdx.x >= (unsigned)Tseg) {
    const int zb = blockIdx.x - Tseg;
    if (threadIdx.x < 256) zstate[zb * 256 + threadIdx.x] = (float4_t){0.f, 0.f, 0.f, 0.f};
    if (zb == 0 && threadIdx.x == 511) out[0] = 0.f;
    return;
  }
  xg_body(blockIdx.x, threadIdx.x, kmers, emb, w_ih_f, b_ih_f, b_hh_f, w_ih_b, b_ih_b, b_hh_b,
          xgbuf, s, Tseg);
}

// ---------------------------------------------------------------- fused: lstm(s) + xg(s+1) or emis
// R4/R6-proven 512-thread structure (162.7 us/dispatch, VGPR 76): blocks 0..15 = one
// (dir,chunk) LSTM chain each (8 waves). Blocks >= 16: sx>=0 -> xg unit (blockIdx-16);
// sx<0 -> TWO emis units per block for rows t in [256,768) (both h_cat halves complete
// after segments 0-2), hiding half of emis under the last lstm dispatch's idle 240 CUs.
// LSTM_STEP is the exact R6 4-deep chain — R10's 2-deep split REGRESSED (+9%): issue-bound.
// R7-R9: 1024-thread blocks are pinned to a 64-VGPR cap by this toolchain (spills); don't.
__global__ __launch_bounds__(512, 2) void lstm_xg_kernel(
    const _Float16* __restrict__ xgrd, _Float16* __restrict__ xgwr,
    const int* __restrict__ kmers, const float* __restrict__ emb,
    const float* __restrict__ w_hh_f, const float* __restrict__ w_hh_b,
    const float* __restrict__ w_ih_f, const float* __restrict__ b_ih_f, const float* __restrict__ b_hh_f,
    const float* __restrict__ w_ih_b, const float* __restrict__ b_ih_b, const float* __restrict__ b_hh_b,
    _Float16* __restrict__ h_cat, _Float16* __restrict__ h_state, float* __restrict__ c_state,
    const float* __restrict__ w_proj, const float* __restrict__ b_proj,
    float* __restrict__ em, _Float16* __restrict__ expem,
    int s, int sx, int Tseg) {
  __shared__ _Float16 A[2][16 * ASTR];
  if (blockIdx.x >= 16) {
    if (sx >= 0) {
      xg_body(blockIdx.x - 16, threadIdx.x, kmers, emb, w_ih_f, b_ih_f, b_hh_f, w_ih_b, b_ih_b,
              b_hh_b, xgwr, sx, Tseg);
    } else {
      const int u = 512 + (blockIdx.x - 16) * 2 + (threadIdx.x >> 8);
      emis_unit(u, threadIdx.x & 255, h_cat, w_proj, b_proj, em, expem);
    }
    return;
  }
  const int wg = blockIdx.x;
  const int dir = wg >> 3, chunk = wg & 7;
  const int b0 = chunk * 16;
  const float* w_hh = dir ? w_hh_b : w_hh_f;
  const int tid = threadIdx.x;
  const int wave = tid >> 6, lane = tid & 63;
  const int n16 = lane & 15, quad = lane >> 4;

  half8_t wf[4][4];
#pragma unroll
  for (int g = 0; g < 4; ++g) {
    const int row = g * HH + wave * 16 + n16;
#pragma unroll
    for (int kf = 0; kf < 4; ++kf) {
      const float* src = w_hh + row * HH + kf * 32 + quad * 8;
#pragma unroll
      for (int i = 0; i < 8; ++i) wf[g][kf][i] = (_Float16)src[i];
    }
  }
  // persistent state: layout identical to R5 ((dir*8+chunk)*8+wave)
  const int sidx = ((wg * 8 + wave) * 64 + lane) * 4;
  half4_t h4 = *(const half4_t*)(h_state + sidx);
  float4_t c4 = *(const float4_t*)(c_state + sidx);
  half2_t c2[2];
  c2[0] = cvt_pk(c4[0], c4[1]);
  c2[1] = cvt_pk(c4[2], c4[3]);
  *(half4_t*)(&A[0][n16 * ASTR + wave * 16 + quad * 4]) = h4;  // seed h_{-1}

  const _Float16* xgw =
      xgrd + (size_t)dir * Tseg * 65536 + chunk * 8192 + wave * 1024 + (size_t)lane * 16;
  half4_t hlast = h4;
  const float4_t z4 = {0.f, 0.f, 0.f, 0.f};
  const int te0 = dir ? (TT - 1 - s * Tseg) : (s * Tseg);
  _Float16* gp_run =
      h_cat + ((size_t)te0 * BB + b0 + n16) * 256 + dir * HH + wave * 16 + quad * 4;
  const ptrdiff_t dstep = dir ? -(ptrdiff_t)32768 : (ptrdiff_t)32768;

  // 4-deep in-place xg prefetch ring (static indices)
  half8_t pf0[4], pf1[4];
#pragma unroll
  for (int j = 0; j < 4; ++j) {
    const _Float16* p = xgw + (size_t)j * 65536;
    pf0[j] = *(const half8_t*)p;
    pf1[j] = *(const half8_t*)(p + 8);
  }

#define LSTM_STEP(AB, AN, X0, X1)                                                          \
  {                                                                                        \
    const _Float16* Abp = &AB[0];                                                          \
    _Float16* Anp = &AN[0];                                                                \
    half8_t hb0 = *(const half8_t*)(Abp + n16 * ASTR + 0 * 32 + quad * 8);                 \
    half8_t hb1 = *(const half8_t*)(Abp + n16 * ASTR + 1 * 32 + quad * 8);                 \
    half8_t hb2 = *(const half8_t*)(Abp + n16 * ASTR + 2 * 32 + quad * 8);                 \
    half8_t hb3 = *(const half8_t*)(Abp + n16 * ASTR + 3 * 32 + quad * 8);                 \
    float4_t acc[4];                                                                       \
    _Pragma("unroll") for (int g = 0; g < 4; ++g) {                                        \
      acc[g] = __builtin_amdgcn_mfma_f32_16x16x32_f16(wf[g][0], hb0, z4, 0, 0, 0);         \
    }                                                                                      \
    _Pragma("unroll") for (int g = 0; g < 4; ++g) {                                        \
      acc[g] = __builtin_amdgcn_mfma_f32_16x16x32_f16(wf[g][1], hb1, acc[g], 0, 0, 0);     \
    }                                                                                      \
    _Pragma("unroll") for (int g = 0; g < 4; ++g) {                                        \
      acc[g] = __builtin_amdgcn_mfma_f32_16x16x32_f16(wf[g][2], hb2, acc[g], 0, 0, 0);     \
    }                                                                                      \
    _Pragma("unroll") for (int g = 0; g < 4; ++g) {                                        \
      acc[g] = __builtin_amdgcn_mfma_f32_16x16x32_f16(wf[g][3], hb3, acc[g], 0, 0, 0);     \
    }                                                                                      \
    const half2_t* x0p = (const half2_t*)&X0;                                              \
    const half2_t* x1p = (const half2_t*)&X1;                                              \
    half4_t hstore;                                                                        \
    _Pragma("unroll") for (int p = 0; p < 2; ++p) {                                        \
      const half2_t i_ = sig6(cvt_pk(acc[0][2 * p], acc[0][2 * p + 1]) + x0p[p]);          \
      const half2_t f_ = sig6(cvt_pk(acc[1][2 * p], acc[1][2 * p + 1]) + x0p[2 + p]);      \
      const half2_t g_ = tanh6(cvt_pk(acc[2][2 * p], acc[2][2 * p + 1]) + x1p[p]);         \
      const half2_t o_ = sig6(cvt_pk(acc[3][2 * p], acc[3][2 * p + 1]) + x1p[2 + p]);      \
      c2[p] = f_ * c2[p] + i_ * g_;                                                        \
      const half2_t hh = o_ * tanh6(c2[p]);                                                \
      hstore[2 * p] = hh[0];                                                               \
      hstore[2 * p + 1] = hh[1];                                                           \
    }                                                                                      \
    *(half4_t*)(Anp + n16 * ASTR + wave * 16 + quad * 4) = hstore;                         \
    *(half4_t*)gp_run = hstore;                                                            \
    hlast = hstore;                                                                        \
  }

  // main loop: prefetch il+j+4 <= Tseg-1, no clamp needed
  for (int il = 0; il < Tseg - 4; il += 4) {
#pragma unroll
    for (int j = 0; j < 4; ++j) {
      lds_barrier();
      if (j & 1) {
        LSTM_STEP(A[1], A[0], pf0[j], pf1[j]);
      } else {
        LSTM_STEP(A[0], A[1], pf0[j], pf1[j]);
      }
      const _Float16* p = xgw + (size_t)(il + j + 4) * 65536;
      pf0[j] = *(const half8_t*)p;
      pf1[j] = *(const half8_t*)(p + 8);
      gp_run += dstep;
    }
  }
  // tail: last 4 steps, no prefetch
#pragma unroll
  for (int j = 0; j < 4; ++j) {
    lds_barrier();
    if (j & 1) {
      LSTM_STEP(A[1], A[0], pf0[j], pf1[j]);
    } else {
      LSTM_STEP(A[0], A[1], pf0[j], pf1[j]);
    }
    gp_run += dstep;
  }
#undef LSTM_STEP

  *(half4_t*)(h_state + sidx) = hlast;
  c4[0] = (float)c2[0][0]; c4[1] = (float)c2[0][1];
  c4[2] = (float)c2[1][0]; c4[3] = (float)c2[1][1];
  *(float4_t*)(c_state + sidx) = c4;
}

// ---------------------------------------------------------------- emissions (standalone)
// mode 0: full 2048 units (grid 1024). mode 1: units 0..511 and 1536..2047 (grid 512) —
// the middle 1024 were computed inside the last lstm dispatch.
__global__ __launch_bounds__(512) void emis_kernel(const _Float16* __restrict__ h_cat,
                                                   const float* __restrict__ w_proj,
                                                   const float* __restrict__ b_proj,
                                                   float* __restrict__ em,
                                                   _Float16* __restrict__ expem, int mode) {
  int u = blockIdx.x * 2 + (threadIdx.x >> 8);
  if (mode) u = (u < 512) ? u : u + 1024;
  emis_unit(u, threadIdx.x & 255, h_cat, w_proj, b_proj, em, expem);
}

// ---------------------------------------------------------------- segment-parallel CRF matrices
// 2048 chains (128 batches x 16 segments), 1 wave each: N <- diag(g_t) (E^T N), N init = I.
// Stored as Nbuf[b][s][c][k] = N[k][c] = P_s[c][k]. Blocks >= 2048: CRF numerator.
__global__ __launch_bounds__(64) void mcrf_kernel(const float* __restrict__ em,
                                                  const _Float16* __restrict__ expem,
                                                  const float* __restrict__ trans,
                                                  const int* __restrict__ tags,
                                                  const float* __restrict__ start_trans,
                                                  const float* __restrict__ end_trans,
                                                  _Float16* __restrict__ Nbuf,
                                                  float* __restrict__ lzbuf,
                                                  float* __restrict__ num) {
  const int lane = threadIdx.x;
  if (blockIdx.x >= 2048) {  // ---------------- numerator (1 wave per batch)
    const int nb = blockIdx.x - 2048;
    const int tg = tags[nb];
    float acc = 0.f;
    for (int t = lane; t < TT; t += 64)
      acc += em[((size_t)t * BB + nb) * NTAG + tg];
#pragma unroll
    for (int off = 32; off > 0; off >>= 1) acc += __shfl_xor(acc, off, 64);
    if (lane == 0)
      num[nb] = start_trans[tg] + end_trans[tg] + 1023.0f * trans[tg * NTAG + tg] + acc;
    return;
  }
  const int n16 = lane & 15, quad = lane >> 4;
  const int b = blockIdx.x >> 4;
  const int s = blockIdx.x & 15;

  half8_t efA[4][2];
#pragma unroll
  for (int mt = 0; mt < 4; ++mt)
#pragma unroll
    for (int kf = 0; kf < 2; ++kf)
#pragma unroll
      for (int i = 0; i < 8; ++i) {
        const int m = mt * 16 + n16, k = kf * 32 + quad * 8 + i;
        efA[mt][kf][i] = (_Float16)(fast_exp(trans[k * NTAG + m]) * 0.015625f);
      }

  half8_t pb[4][2];
#pragma unroll
  for (int tile = 0; tile < 4; ++tile)
#pragma unroll
    for (int kf = 0; kf < 2; ++kf)
#pragma unroll
      for (int i = 0; i < 8; ++i) {
        const int k = kf * 32 + quad * 8 + i;
        pb[tile][kf][i] = (_Float16)((k == tile * 16 + n16) ? 1.f : 0.f);
      }

  float lz2 = 0.f;
  const float4_t z4 = {0.f, 0.f, 0.f, 0.f};
  const _Float16* exb = expem + (size_t)b * NTAG;
  const int t0 = s * 64 + 1;
  const int nsteps = (s == 15) ? 63 : 64;

#define MCRF_CORE(PB0, PB1, NB0, NB1)                                                      \
  {                                                                                        \
    float4_t a0 = __builtin_amdgcn_mfma_f32_16x16x32_f16(efA[0][0], PB0, z4, 0, 0, 0);     \
    float4_t a1 = __builtin_amdgcn_mfma_f32_16x16x32_f16(efA[1][0], PB0, z4, 0, 0, 0);     \
    float4_t a2 = __builtin_amdgcn_mfma_f32_16x16x32_f16(efA[2][0], PB0, z4, 0, 0, 0);     \
    float4_t a3 = __builtin_amdgcn_mfma_f32_16x16x32_f16(efA[3][0], PB0, z4, 0, 0, 0);     \
    a0 = __builtin_amdgcn_mfma_f32_16x16x32_f16(efA[0][1], PB1, a0, 0, 0, 0);              \
    a1 = __builtin_amdgcn_mfma_f32_16x16x32_f16(efA[1][1], PB1, a1, 0, 0, 0);              \
    a2 = __builtin_amdgcn_mfma_f32_16x16x32_f16(efA[2][1], PB1, a2, 0, 0, 0);              \
    a3 = __builtin_amdgcn_mfma_f32_16x16x32_f16(efA[3][1], PB1, a3, 0, 0, 0);              \
    half2_t dpk[4][2];                                                                     \
    dpk[0][0] = cvt_pk(a0[0], a0[1]); dpk[0][1] = cvt_pk(a0[2], a0[3]);                    \
    dpk[1][0] = cvt_pk(a1[0], a1[1]); dpk[1][1] = cvt_pk(a1[2], a1[3]);                    \
    dpk[2][0] = cvt_pk(a2[0], a2[1]); dpk[2][1] = cvt_pk(a2[2], a2[3]);                    \
    dpk[3][0] = cvt_pk(a3[0], a3[1]); dpk[3][1] = cvt_pk(a3[2], a3[3]);                    \
    half2_t* wwp0 = (half2_t*)&NB0;                                                        \
    half2_t* wwp1 = (half2_t*)&NB1;                                                        \
    _Pragma("unroll") for (int kf = 0; kf < 2; ++kf) {                                     \
      half2_t* wp = kf ? wwp1 : wwp0;                                                      \
      _Pragma("unroll") for (int p = 0; p < 2; ++p) {                                      \
        const unsigned Xu = __builtin_bit_cast(unsigned, dpk[2 * kf][p]);                  \
        const unsigned Yu = __builtin_bit_cast(unsigned, dpk[2 * kf + 1][p]);              \
        uint2_t r1 = __builtin_amdgcn_permlane32_swap(Xu, Yu, false, false);               \
        uint2_t r2 = __builtin_amdgcn_permlane16_swap(r1[0], r1[1], false, false);         \
        wp[p] = __builtin_bit_cast(half2_t, r2[0]);                                        \
        wp[2 + p] = __builtin_bit_cast(half2_t, r2[1]);                                    \
      }                                                                                    \
    }                                                                                      \
  }

#define MSTEP(GC0, GC1, IT)                                                                \
  {                                                                                        \
    _Pragma("unroll") for (int tile = 0; tile < 4; ++tile) {                               \
      half8_t nb0, nb1;                                                                    \
      MCRF_CORE(pb[tile][0], pb[tile][1], nb0, nb1)                                        \
      pb[tile][0] = nb0 * GC0;                                                             \
      pb[tile][1] = nb1 * GC1;                                                             \
    }                                                                                      \
    if (((IT) & 15) == 15) {                                                               \
      half8_t m8 = __builtin_elementwise_max(pb[0][0], pb[0][1]);                          \
      m8 = __builtin_elementwise_max(m8, __builtin_elementwise_max(pb[1][0], pb[1][1]));   \
      m8 = __builtin_elementwise_max(m8, __builtin_elementwise_max(pb[2][0], pb[2][1]));   \
      m8 = __builtin_elementwise_max(m8, __builtin_elementwise_max(pb[3][0], pb[3][1]));   \
      float mm = (float)m8[0];                                                             \
      _Pragma("unroll") for (int i = 1; i < 8; ++i) mm = fmaxf(mm, (float)m8[i]);          \
      mm = quad_max4(mm);                                                                  \
      mm = fmaxf(mm, __shfl_xor(mm, 1, 64));                                               \
      mm = fmaxf(mm, __shfl_xor(mm, 2, 64));                                               \
      mm = fmaxf(mm, __shfl_xor(mm, 4, 64));                                               \
      mm = fmaxf(mm, __shfl_xor(mm, 8, 64));                                               \
      lz2 += __builtin_amdgcn_logf(mm);                                                    \
      const half8_t rc8 = h8bc(__builtin_amdgcn_rcpf(mm));                                 \
      _Pragma("unroll") for (int tile = 0; tile < 4; ++tile) {                             \
        pb[tile][0] *= rc8;                                                                \
        pb[tile][1] *= rc8;                                                                \
      }                                                                                    \
    }                                                                                      \
  }

  half8_t pre0[4], pre1[4];
#pragma unroll
  for (int j = 0; j < 4; ++j) {
    const size_t tt = (size_t)(t0 + j) * 8192;
    pre0[j] = *(const half8_t*)(exb + tt + quad * 8);
    pre1[j] = *(const half8_t*)(exb + tt + 32 + quad * 8);
  }
  int it = 0;
  const int full4 = nsteps >> 2;
  for (int grp = 0; grp < full4; ++grp) {
#pragma unroll
    for (int j = 0; j < 4; ++j) {
      const half8_t gc0 = pre0[j], gc1 = pre1[j];
      int tf = t0 + it + 4;
      tf = tf > 1023 ? 1023 : tf;
      const size_t tt = (size_t)tf * 8192;
      pre0[j] = *(const half8_t*)(exb + tt + quad * 8);
      pre1[j] = *(const half8_t*)(exb + tt + 32 + quad * 8);
      MSTEP(gc0, gc1, it)
      ++it;
    }
  }
  for (; it < nsteps; ++it) {
    const size_t tt = (size_t)(t0 + it) * 8192;
    const half8_t gc0 = *(const half8_t*)(exb + tt + quad * 8);
    const half8_t gc1 = *(const half8_t*)(exb + tt + 32 + quad * 8);
    MSTEP(gc0, gc1, it)
  }
#undef MSTEP
#undef MCRF_CORE

  _Float16* nb = Nbuf + ((size_t)b * 16 + s) * 4096;
#pragma unroll
  for (int tile = 0; tile < 4; ++tile) {
    const int col = tile * 16 + n16;
#pragma unroll
    for (int kf = 0; kf < 2; ++kf)
      *(half8_t*)(nb + (size_t)col * 64 + kf * 32 + quad * 8) = pb[tile][kf];
  }
  if (lane == 0) lzbuf[b * 16 + s] = lz2;
}

// ---------------------------------------------------------------- merge: w <- P_s w, alpha0 dot,
// then atomically accumulate (denom_b - num_b) into out[0] (zeroed by the xg0 launch).
__global__ __launch_bounds__(64) void merge_kernel(const _Float16* __restrict__ Nbuf,
                                                   const float* __restrict__ lzbuf,
                                                   const float* __restrict__ em,
                                                   const float* __restrict__ start_trans,
                                                   const float* __restrict__ end_trans,
                                                   const float* __restrict__ num,
                                                   float* __restrict__ out) {
  const int b = blockIdx.x, m = threadIdx.x;
  __shared__ float w[64];
  float L2 = 0.f;
  w[m] = fast_exp(end_trans[m]);
  for (int s = 15; s >= 0; --s) {
    lds_fence();
    const _Float16* row = Nbuf + (((size_t)b * 16 + s) * 64 + m) * 64;
    float acc = 0.f;
#pragma unroll
    for (int kf = 0; kf < 8; ++kf) {
      const half8_t rv = *(const half8_t*)(row + kf * 8);
#pragma unroll
      for (int i = 0; i < 8; ++i) acc += (float)rv[i] * w[kf * 8 + i];
    }
    float mx = acc;
#pragma unroll
    for (int off = 32; off > 0; off >>= 1) mx = fmaxf(mx, __shfl_xor(mx, off, 64));
    L2 += __builtin_amdgcn_logf(mx) + lzbuf[b * 16 + s];
    const float inv = __builtin_amdgcn_rcpf(mx);
    lds_fence();
    w[m] = acc * inv;
  }
  lds_fence();
  const float sv = start_trans[m] + em[(size_t)b * NTAG + m];  // t=0 row
  float m0 = sv;
#pragma unroll
  for (int off = 32; off > 0; off >>= 1) m0 = fmaxf(m0, __shfl_xor(m0, off, 64));
  float z = fast_exp(sv - m0) * w[m];
#pragma unroll
  for (int off = 32; off > 0; off >>= 1) z += __shfl_xor(z, off, 64);
  if (m == 0) {
    const float denomv =
        m0 + 0.693147180559945f * (L2 + 6138.0f + __builtin_amdgcn_logf(z));
    atomicAdd(out, denomv - num[b]);
  }
}

extern "C" void kernel_launch(void* const* d_in, const int* in_sizes, int n_in,
                              void* d_out, int out_size, void* d_ws, size_t ws_size,
                              hipStream_t stream) {
  const int* kmers = (const int*)d_in[0];
  const int* tags = (const int*)d_in[1];
  const float* emb = (const float*)d_in[2];
  const float* w_ih_f = (const float*)d_in[3];
  const float* w_hh_f = (const float*)d_in[4];
  const float* b_ih_f = (const float*)d_in[5];
  const float* b_hh_f = (const float*)d_in[6];
  const float* w_ih_b = (const float*)d_in[7];
  const float* w_hh_b = (const float*)d_in[8];
  const float* b_ih_b = (const float*)d_in[9];
  const float* b_hh_b = (const float*)d_in[10];
  const float* w_proj = (const float*)d_in[11];
  const float* b_proj = (const float*)d_in[12];
  const float* start_trans = (const float*)d_in[13];
  const float* end_trans = (const float*)d_in[14];
  const float* trans = (const float*)d_in[15];

  char* ws = (char*)d_ws;
  _Float16* h_cat = (_Float16*)(ws + 33554432);    // [33.5M, 100.7M)
  float* em = (float*)ws;                          // [0, 33.5M) — x buffer is gone
  float* out = (float*)d_out;
  // post-emis overlays of the dead h_cat region (path-independent):
  _Float16* Nbuf = (_Float16*)(ws + 33554432);            // 16.8 MB
  float* lzbuf = (float*)(ws + 33554432 + 16777216);      // 8 KB
  float* num = (float*)(ws + 33554432 + 16785920);        // 512 B

  const bool fused = ws_size >= 235078656ull;
  if (fused) {
    const int Tseg = 256;
    _Float16* buf0 = (_Float16*)(ws + 100663296);              // 64 MB
    _Float16* buf1 = (_Float16*)(ws + 100663296 + 67108864);   // 64 MB
    _Float16* expem = (_Float16*)(ws + 100663296);             // aliases buf0 (dead after lstm)
    _Float16* h_state = (_Float16*)(ws + 100663296 + 134217728);
    float* c_state = (float*)(ws + 100663296 + 134217728 + 65536);

    hipLaunchKernelGGL(xg_kernel, dim3(Tseg + 49), dim3(512), 0, stream, kmers, emb,
                       w_ih_f, b_ih_f, b_hh_f, w_ih_b, b_ih_b, b_hh_b, buf0, 0, Tseg,
                       (float4_t*)h_state, out);
    for (int s = 0; s < 3; ++s) {
      _Float16* rd = (s & 1) ? buf1 : buf0;
      _Float16* wr = (s & 1) ? buf0 : buf1;
      hipLaunchKernelGGL(lstm_xg_kernel, dim3(16 + Tseg), dim3(512), 0, stream,
                         (const _Float16*)rd, wr, kmers, emb, w_hh_f, w_hh_b,
                         w_ih_f, b_ih_f, b_hh_f, w_ih_b, b_ih_b, b_hh_b,
                         h_cat, h_state, c_state, w_proj, b_proj, em, expem, s, s + 1, Tseg);
    }
    // last segment: blocks >= 16 compute emis for t in [256,768) (sx = -1)
    hipLaunchKernelGGL(lstm_xg_kernel, dim3(16 + 512), dim3(512), 0, stream,
                       (const _Float16*)buf1, buf0, kmers, emb, w_hh_f, w_hh_b,
                       w_ih_f, b_ih_f, b_hh_f, w_ih_b, b_ih_b, b_hh_b,
                       h_cat, h_state, c_state, w_proj, b_proj, em, expem, 3, -1, Tseg);
    hipLaunchKernelGGL(emis_kernel, dim3(512), dim3(512), 0, stream, h_cat, w_proj, b_proj, em,
                       expem, 1);
    hipLaunchKernelGGL(mcrf_kernel, dim3(2176), dim3(64), 0, stream, em,
                       (const _Float16*)expem, trans, tags, start_trans, end_trans, Nbuf, lzbuf,
                       num);
    hipLaunchKernelGGL(merge_kernel, dim3(128), dim3(64), 0, stream, (const _Float16*)Nbuf,
                       lzbuf, em, start_trans, end_trans, num, out);
  } else {
    int nseg;
    if (ws_size >= 167969792ull) nseg = 4;
    else if (ws_size >= 134415360ull) nseg = 8;
    else nseg = 16;
    const int Tseg = TT / nseg;
    const size_t xg_bytes = 268435456ull / (size_t)nseg;
    _Float16* xgbuf = (_Float16*)(ws + 100663296);
    _Float16* expem = (_Float16*)(ws + 100663296);
    _Float16* h_state = (_Float16*)(ws + 100663296 + xg_bytes);
    float* c_state = (float*)(ws + 100663296 + xg_bytes + 65536);

    for (int s = 0; s < nseg; ++s) {
      const int extra = (s == 0) ? 49 : 0;  // state/out zeroing rides the first xg launch
      hipLaunchKernelGGL(xg_kernel, dim3(Tseg + extra), dim3(512), 0, stream, kmers, emb,
                         w_ih_f, b_ih_f, b_hh_f, w_ih_b, b_ih_b, b_hh_b, xgbuf, s, Tseg,
                         (float4_t*)h_state, out);
      hipLaunchKernelGGL(lstm_xg_kernel, dim3(16), dim3(512), 0, stream,
                         (const _Float16*)xgbuf, xgbuf, kmers, emb, w_hh_f, w_hh_b,
                         w_ih_f, b_ih_f, b_hh_f, w_ih_b, b_ih_b, b_hh_b,
                         h_cat, h_state, c_state, w_proj, b_proj, em, expem, s, 0, Tseg);
    }
    hipLaunchKernelGGL(emis_kernel, dim3(1024), dim3(512), 0, stream, h_cat, w_proj, b_proj, em,
                       expem, 0);
    hipLaunchKernelGGL(mcrf_kernel, dim3(2176), dim3(64), 0, stream, em,
                       (const _Float16*)expem, trans, tags, start_trans, end_trans, Nbuf, lzbuf,
                       num);
    hipLaunchKernelGGL(merge_kernel, dim3(128), dim3(64), 0, stream, (const _Float16*)Nbuf,
                       lzbuf, em, start_trans, end_trans, num, out);
  }
}